// Round 1
// baseline (1020.133 us; speedup 1.0000x reference)
//
#include <hip/hip_runtime.h>
#include <hip/hip_bf16.h>

#define N_NODES 100000
#define N_EDGES 3200000
#define IN_F 256
#define HID 128
#define OUT_F 8

// ---------------------------------------------------------------------------
// CSR build: histogram of dst, bucket allocation (order-free), scatter src ids
// ---------------------------------------------------------------------------
__global__ __launch_bounds__(256) void k_hist(const int* __restrict__ dst,
                                              int* __restrict__ cnt, int E) {
    int e = blockIdx.x * 256 + threadIdx.x;
    if (e < E) atomicAdd(&cnt[dst[e]], 1);
}

// Per-wave inclusive scan of counts, one atomicAdd per wave on a global cursor.
// Bucket placement order across nodes is arbitrary — aggregation only needs
// offs[v]/cnt[v], never assumes buckets are in node order.
__global__ __launch_bounds__(256) void k_alloc(const int* __restrict__ cnt,
                                               int* __restrict__ offs,
                                               int* __restrict__ cursor,
                                               float* __restrict__ dinv,
                                               int* __restrict__ total, int N) {
    int v = blockIdx.x * 256 + threadIdx.x;
    int lane = threadIdx.x & 63;
    int c = (v < N) ? cnt[v] : 0;
    int s = c;
    #pragma unroll
    for (int d = 1; d < 64; d <<= 1) {
        int t = __shfl_up(s, d);
        if (lane >= d) s += t;
    }
    int wtot = __shfl(s, 63);
    int base = 0;
    if (lane == 63) base = atomicAdd(total, wtot);
    base = __shfl(base, 63);
    if (v < N) {
        int off = base + s - c;   // exclusive within wave + wave base
        offs[v] = off;
        cursor[v] = off;
        dinv[v] = rsqrtf((float)(c + 1));   // +1 self-loop; >=1 always
    }
}

__global__ __launch_bounds__(256) void k_scatter(const int* __restrict__ src,
                                                 const int* __restrict__ dst,
                                                 int* __restrict__ cursor,
                                                 int* __restrict__ ssrc, int E) {
    int e = blockIdx.x * 256 + threadIdx.x;
    if (e < E) {
        int d = dst[e];
        int p = atomicAdd(&cursor[d], 1);
        ssrc[p] = src[e];
    }
}

// ---------------------------------------------------------------------------
// GEMM1: H[100000,128] = X[100000,256] @ W1[256,128]   (fp32 vector ALU)
// Block: 256 threads -> 64-row x 128-col tile; thread computes 8x4.
// A staged transposed in LDS so fragment reads are float4.
// ---------------------------------------------------------------------------
__global__ __launch_bounds__(256) void k_gemm1(const float* __restrict__ X,
                                               const float* __restrict__ W,
                                               float* __restrict__ H, int M) {
    __shared__ float xs[16][68];     // [k][row], +4 pad keeps 16B alignment, 2-way max
    __shared__ float ws[16 * 128];   // [k][col]
    int t  = threadIdx.x;
    int tx = t & 31;    // col group (4 cols)
    int ty = t >> 5;    // row group (8 rows)
    int row0 = blockIdx.x * 64;

    int lrow = t >> 2;          // 0..63
    int lk   = (t & 3) * 4;     // 0,4,8,12
    int grow = row0 + lrow;
    if (grow >= M) grow = M - 1;               // clamp; OOB rows never stored
    const float* xrow = X + (size_t)grow * IN_F;

    float acc[8][4];
    #pragma unroll
    for (int m = 0; m < 8; m++)
        #pragma unroll
        for (int n = 0; n < 4; n++) acc[m][n] = 0.f;

    for (int k0 = 0; k0 < IN_F; k0 += 16) {
        float4 xv = *(const float4*)(xrow + k0 + lk);
        int kk0 = t >> 5, c4 = t & 31;
        float4 wv0 = *(const float4*)(W + (size_t)(k0 + kk0) * HID + c4 * 4);
        float4 wv1 = *(const float4*)(W + (size_t)(k0 + 8 + kk0) * HID + c4 * 4);
        __syncthreads();
        xs[lk + 0][lrow] = xv.x;
        xs[lk + 1][lrow] = xv.y;
        xs[lk + 2][lrow] = xv.z;
        xs[lk + 3][lrow] = xv.w;
        *(float4*)&ws[(kk0) * HID + c4 * 4]     = wv0;
        *(float4*)&ws[(kk0 + 8) * HID + c4 * 4] = wv1;
        __syncthreads();
        const float4* wsf4 = (const float4*)ws;
        #pragma unroll
        for (int kk = 0; kk < 16; kk++) {
            float4 b  = wsf4[kk * 32 + tx];
            float4 a0 = *(const float4*)&xs[kk][ty * 8];
            float4 a1 = *(const float4*)&xs[kk][ty * 8 + 4];
            acc[0][0] = fmaf(a0.x, b.x, acc[0][0]); acc[0][1] = fmaf(a0.x, b.y, acc[0][1]);
            acc[0][2] = fmaf(a0.x, b.z, acc[0][2]); acc[0][3] = fmaf(a0.x, b.w, acc[0][3]);
            acc[1][0] = fmaf(a0.y, b.x, acc[1][0]); acc[1][1] = fmaf(a0.y, b.y, acc[1][1]);
            acc[1][2] = fmaf(a0.y, b.z, acc[1][2]); acc[1][3] = fmaf(a0.y, b.w, acc[1][3]);
            acc[2][0] = fmaf(a0.z, b.x, acc[2][0]); acc[2][1] = fmaf(a0.z, b.y, acc[2][1]);
            acc[2][2] = fmaf(a0.z, b.z, acc[2][2]); acc[2][3] = fmaf(a0.z, b.w, acc[2][3]);
            acc[3][0] = fmaf(a0.w, b.x, acc[3][0]); acc[3][1] = fmaf(a0.w, b.y, acc[3][1]);
            acc[3][2] = fmaf(a0.w, b.z, acc[3][2]); acc[3][3] = fmaf(a0.w, b.w, acc[3][3]);
            acc[4][0] = fmaf(a1.x, b.x, acc[4][0]); acc[4][1] = fmaf(a1.x, b.y, acc[4][1]);
            acc[4][2] = fmaf(a1.x, b.z, acc[4][2]); acc[4][3] = fmaf(a1.x, b.w, acc[4][3]);
            acc[5][0] = fmaf(a1.y, b.x, acc[5][0]); acc[5][1] = fmaf(a1.y, b.y, acc[5][1]);
            acc[5][2] = fmaf(a1.y, b.z, acc[5][2]); acc[5][3] = fmaf(a1.y, b.w, acc[5][3]);
            acc[6][0] = fmaf(a1.z, b.x, acc[6][0]); acc[6][1] = fmaf(a1.z, b.y, acc[6][1]);
            acc[6][2] = fmaf(a1.z, b.z, acc[6][2]); acc[6][3] = fmaf(a1.z, b.w, acc[6][3]);
            acc[7][0] = fmaf(a1.w, b.x, acc[7][0]); acc[7][1] = fmaf(a1.w, b.y, acc[7][1]);
            acc[7][2] = fmaf(a1.w, b.z, acc[7][2]); acc[7][3] = fmaf(a1.w, b.w, acc[7][3]);
        }
    }
    #pragma unroll
    for (int m = 0; m < 8; m++) {
        int r = row0 + ty * 8 + m;
        if (r < M) {
            float4 o = make_float4(acc[m][0], acc[m][1], acc[m][2], acc[m][3]);
            *(float4*)&H[(size_t)r * HID + tx * 4] = o;
        }
    }
}

// ---------------------------------------------------------------------------
// Aggregation layer 1: wave per node, float2 per lane (128 feats / 64 lanes).
// a1[v] = relu(dinv[v]*(sum_{s in N(v)} h1[s]*dinv[s] + h1[v]*dinv[v]) + b1)
// ---------------------------------------------------------------------------
__global__ __launch_bounds__(256) void k_agg1(const float* __restrict__ h1,
                                              const int* __restrict__ offs,
                                              const int* __restrict__ cnt,
                                              const float* __restrict__ dinv,
                                              const int* __restrict__ ssrc,
                                              const float* __restrict__ b1,
                                              float* __restrict__ a1, int N) {
    int wid = (blockIdx.x * 256 + threadIdx.x) >> 6;
    int lane = threadIdx.x & 63;
    if (wid >= N) return;
    float dv = dinv[wid];
    const float2* hp = (const float2*)h1;
    float2 self = hp[(size_t)wid * 64 + lane];
    float ax = self.x * dv, ay = self.y * dv;
    int beg = offs[wid], n = cnt[wid];
    for (int j = 0; j < n; j++) {
        int s = ssrc[beg + j];
        float w = dinv[s];
        float2 tv = hp[(size_t)s * 64 + lane];
        ax = fmaf(tv.x, w, ax);
        ay = fmaf(tv.y, w, ay);
    }
    float2 bb = ((const float2*)b1)[lane];
    float ox = fmaxf(fmaf(ax, dv, bb.x), 0.f);
    float oy = fmaxf(fmaf(ay, dv, bb.y), 0.f);
    ((float2*)a1)[(size_t)wid * 64 + lane] = make_float2(ox, oy);
}

// ---------------------------------------------------------------------------
// GEMM2: h2[100000,8] = a1[100000,128] @ W2[128,8]; W2 in LDS.
// thread = (node, feat); 32 nodes per 256-thread block.
// ---------------------------------------------------------------------------
__global__ __launch_bounds__(256) void k_gemm2(const float* __restrict__ a1,
                                               const float* __restrict__ W2,
                                               float* __restrict__ h2, int N) {
    __shared__ float w[HID * OUT_F];
    int t = threadIdx.x;
    for (int i = t; i < HID * OUT_F; i += 256) w[i] = W2[i];
    __syncthreads();
    int node = blockIdx.x * 32 + (t >> 3);
    int f = t & 7;
    if (node >= N) return;
    const float* ar = a1 + (size_t)node * HID;
    float acc = 0.f;
    #pragma unroll 8
    for (int k = 0; k < HID; k++) acc = fmaf(ar[k], w[k * OUT_F + f], acc);
    h2[(size_t)node * OUT_F + f] = acc;
}

// ---------------------------------------------------------------------------
// Aggregation layer 2 + bias + log_softmax, fused. Wave per node:
// lane = (edge_group 0..7) * 8 + feat 0..7. Xor-shuffle reductions.
// ---------------------------------------------------------------------------
__global__ __launch_bounds__(256) void k_agg2(const float* __restrict__ h2,
                                              const int* __restrict__ offs,
                                              const int* __restrict__ cnt,
                                              const float* __restrict__ dinv,
                                              const int* __restrict__ ssrc,
                                              const float* __restrict__ b2,
                                              float* __restrict__ out, int N) {
    int wid = (blockIdx.x * 256 + threadIdx.x) >> 6;
    int lane = threadIdx.x & 63;
    if (wid >= N) return;
    int f = lane & 7, g = lane >> 3;
    float dv = dinv[wid];
    int beg = offs[wid], n = cnt[wid];
    float acc = 0.f;
    for (int j = g; j < n; j += 8) {
        int s = ssrc[beg + j];
        acc = fmaf(h2[(size_t)s * OUT_F + f], dinv[s], acc);
    }
    // sum the 8 edge-groups (lanes differing in bits 3..5)
    acc += __shfl_xor(acc, 8);
    acc += __shfl_xor(acc, 16);
    acc += __shfl_xor(acc, 32);
    // self-loop + final norm + bias
    acc = fmaf(h2[(size_t)wid * OUT_F + f], dv, acc);
    acc = fmaf(acc, dv, b2[f]);
    // log_softmax over the 8 feats (lanes differing in bits 0..2)
    float m = acc;
    m = fmaxf(m, __shfl_xor(m, 1));
    m = fmaxf(m, __shfl_xor(m, 2));
    m = fmaxf(m, __shfl_xor(m, 4));
    float e = expf(acc - m);
    float ssum = e;
    ssum += __shfl_xor(ssum, 1);
    ssum += __shfl_xor(ssum, 2);
    ssum += __shfl_xor(ssum, 4);
    float res = acc - m - logf(ssum);
    if (lane < 8) out[(size_t)wid * OUT_F + lane] = res;
}

// ---------------------------------------------------------------------------
extern "C" void kernel_launch(void* const* d_in, const int* in_sizes, int n_in,
                              void* d_out, int out_size, void* d_ws, size_t ws_size,
                              hipStream_t stream) {
    const float* x   = (const float*)d_in[0];
    const int*   ei  = (const int*)d_in[1];     // [2, E] flat: src then dst
    const float* W1  = (const float*)d_in[2];
    const float* b1  = (const float*)d_in[3];
    const float* W2  = (const float*)d_in[4];
    const float* b2  = (const float*)d_in[5];
    float* out = (float*)d_out;

    const int N = N_NODES, E = N_EDGES;
    const int* src = ei;
    const int* dst = ei + E;

    // workspace carve-out (512B aligned)
    char* p = (char*)d_ws;
    auto carve = [&](size_t bytes) -> void* {
        void* r = (void*)p;
        p += (bytes + 511) & ~(size_t)511;
        return r;
    };
    int*   cnt    = (int*)carve((size_t)N * 4);
    int*   offs   = (int*)carve((size_t)N * 4);
    int*   cursor = (int*)carve((size_t)N * 4);
    float* dinv   = (float*)carve((size_t)N * 4);
    int*   total  = (int*)carve(4);
    int*   ssrc   = (int*)carve((size_t)E * 4);
    float* h1     = (float*)carve((size_t)N * HID * 4);
    float* a1     = (float*)carve((size_t)N * HID * 4);
    float* h2     = (float*)carve((size_t)N * OUT_F * 4);

    hipMemsetAsync(cnt, 0, (size_t)N * 4, stream);
    hipMemsetAsync(total, 0, 4, stream);

    int eb = (E + 255) / 256;
    int nb = (N + 255) / 256;

    k_hist<<<eb, 256, 0, stream>>>(dst, cnt, E);
    k_alloc<<<nb, 256, 0, stream>>>(cnt, offs, cursor, dinv, total, N);
    k_scatter<<<eb, 256, 0, stream>>>(src, dst, cursor, ssrc, E);

    k_gemm1<<<(N + 63) / 64, 256, 0, stream>>>(x, W1, h1, N);
    k_agg1<<<(N * 64 + 255) / 256, 256, 0, stream>>>(h1, offs, cnt, dinv, ssrc, b1, a1, N);
    k_gemm2<<<(N + 31) / 32, 256, 0, stream>>>(a1, W2, h2, N);
    k_agg2<<<(N * 64 + 255) / 256, 256, 0, stream>>>(h2, offs, cnt, dinv, ssrc, b2, out, N);
}

// Round 2
// 790.533 us; speedup vs baseline: 1.2904x; 1.2904x over previous
//
#include <hip/hip_runtime.h>
#include <hip/hip_bf16.h>
#include <stdint.h>

#define N_NODES 100000
#define N_EDGES 3200000
#define IN_F 256
#define HID 128
#define OUT_F 8

// bf16 pack/unpack helpers (RNE rounding; finite values only)
__device__ __forceinline__ uint32_t pk_bf16(float a, float b) {
    uint32_t ua = __float_as_uint(a);
    uint32_t ub = __float_as_uint(b);
    ua = (ua + 0x7fff + ((ua >> 16) & 1)) >> 16;          // low half  = a
    ub = (ub + 0x7fff + ((ub >> 16) & 1)) & 0xffff0000u;  // high half = b
    return ua | ub;
}
__device__ __forceinline__ float bl(uint32_t u) { return __uint_as_float(u << 16); }
__device__ __forceinline__ float bh(uint32_t u) { return __uint_as_float(u & 0xffff0000u); }

// ---------------------------------------------------------------------------
// CSR build: histogram of dst, bucket allocation (order-free), scatter src ids
// ---------------------------------------------------------------------------
__global__ __launch_bounds__(256) void k_hist(const int* __restrict__ dst,
                                              int* __restrict__ cnt, int E) {
    int e = blockIdx.x * 256 + threadIdx.x;
    if (e < E) atomicAdd(&cnt[dst[e]], 1);
}

__global__ __launch_bounds__(256) void k_alloc(const int* __restrict__ cnt,
                                               int* __restrict__ offs,
                                               int* __restrict__ cursor,
                                               float* __restrict__ dinv,
                                               int* __restrict__ total, int N) {
    int v = blockIdx.x * 256 + threadIdx.x;
    int lane = threadIdx.x & 63;
    int c = (v < N) ? cnt[v] : 0;
    int s = c;
    #pragma unroll
    for (int d = 1; d < 64; d <<= 1) {
        int t = __shfl_up(s, d);
        if (lane >= d) s += t;
    }
    int wtot = __shfl(s, 63);
    int base = 0;
    if (lane == 63) base = atomicAdd(total, wtot);
    base = __shfl(base, 63);
    if (v < N) {
        int off = base + s - c;
        offs[v] = off;
        cursor[v] = off;
        dinv[v] = rsqrtf((float)(c + 1));   // +1 self-loop
    }
}

__global__ __launch_bounds__(256) void k_scatter(const int* __restrict__ src,
                                                 const int* __restrict__ dst,
                                                 int* __restrict__ cursor,
                                                 int* __restrict__ ssrc, int E) {
    int e = blockIdx.x * 256 + threadIdx.x;
    if (e < E) {
        int d = dst[e];
        int p = atomicAdd(&cursor[d], 1);
        ssrc[p] = src[e];
    }
}

// ---------------------------------------------------------------------------
// GEMM1: H1s[100000,128](bf16) = (X[100000,256] @ W1[256,128]) * dinv[row]
// Block: 256 threads -> 64-row x 128-col tile; thread computes 8x4.
// Epilogue pre-scales by dinv[row] (exact: all consumers use scaled rows),
// then packs to bf16 -> 256B rows for the edge gather.
// ---------------------------------------------------------------------------
__global__ __launch_bounds__(256) void k_gemm1(const float* __restrict__ X,
                                               const float* __restrict__ W,
                                               const float* __restrict__ dinv,
                                               uint32_t* __restrict__ Hs, int M) {
    __shared__ float xs[16][68];
    __shared__ float ws[16 * 128];
    int t  = threadIdx.x;
    int tx = t & 31;    // col group (4 cols)
    int ty = t >> 5;    // row group (8 rows)
    int row0 = blockIdx.x * 64;

    int lrow = t >> 2;
    int lk   = (t & 3) * 4;
    int grow = row0 + lrow;
    if (grow >= M) grow = M - 1;
    const float* xrow = X + (size_t)grow * IN_F;

    float acc[8][4];
    #pragma unroll
    for (int m = 0; m < 8; m++)
        #pragma unroll
        for (int n = 0; n < 4; n++) acc[m][n] = 0.f;

    for (int k0 = 0; k0 < IN_F; k0 += 16) {
        float4 xv = *(const float4*)(xrow + k0 + lk);
        int kk0 = t >> 5, c4 = t & 31;
        float4 wv0 = *(const float4*)(W + (size_t)(k0 + kk0) * HID + c4 * 4);
        float4 wv1 = *(const float4*)(W + (size_t)(k0 + 8 + kk0) * HID + c4 * 4);
        __syncthreads();
        xs[lk + 0][lrow] = xv.x;
        xs[lk + 1][lrow] = xv.y;
        xs[lk + 2][lrow] = xv.z;
        xs[lk + 3][lrow] = xv.w;
        *(float4*)&ws[(kk0) * HID + c4 * 4]     = wv0;
        *(float4*)&ws[(kk0 + 8) * HID + c4 * 4] = wv1;
        __syncthreads();
        const float4* wsf4 = (const float4*)ws;
        #pragma unroll
        for (int kk = 0; kk < 16; kk++) {
            float4 b  = wsf4[kk * 32 + tx];
            float4 a0 = *(const float4*)&xs[kk][ty * 8];
            float4 a1 = *(const float4*)&xs[kk][ty * 8 + 4];
            acc[0][0] = fmaf(a0.x, b.x, acc[0][0]); acc[0][1] = fmaf(a0.x, b.y, acc[0][1]);
            acc[0][2] = fmaf(a0.x, b.z, acc[0][2]); acc[0][3] = fmaf(a0.x, b.w, acc[0][3]);
            acc[1][0] = fmaf(a0.y, b.x, acc[1][0]); acc[1][1] = fmaf(a0.y, b.y, acc[1][1]);
            acc[1][2] = fmaf(a0.y, b.z, acc[1][2]); acc[1][3] = fmaf(a0.y, b.w, acc[1][3]);
            acc[2][0] = fmaf(a0.z, b.x, acc[2][0]); acc[2][1] = fmaf(a0.z, b.y, acc[2][1]);
            acc[2][2] = fmaf(a0.z, b.z, acc[2][2]); acc[2][3] = fmaf(a0.z, b.w, acc[2][3]);
            acc[3][0] = fmaf(a0.w, b.x, acc[3][0]); acc[3][1] = fmaf(a0.w, b.y, acc[3][1]);
            acc[3][2] = fmaf(a0.w, b.z, acc[3][2]); acc[3][3] = fmaf(a0.w, b.w, acc[3][3]);
            acc[4][0] = fmaf(a1.x, b.x, acc[4][0]); acc[4][1] = fmaf(a1.x, b.y, acc[4][1]);
            acc[4][2] = fmaf(a1.x, b.z, acc[4][2]); acc[4][3] = fmaf(a1.x, b.w, acc[4][3]);
            acc[5][0] = fmaf(a1.y, b.x, acc[5][0]); acc[5][1] = fmaf(a1.y, b.y, acc[5][1]);
            acc[5][2] = fmaf(a1.y, b.z, acc[5][2]); acc[5][3] = fmaf(a1.y, b.w, acc[5][3]);
            acc[6][0] = fmaf(a1.z, b.x, acc[6][0]); acc[6][1] = fmaf(a1.z, b.y, acc[6][1]);
            acc[6][2] = fmaf(a1.z, b.z, acc[6][2]); acc[6][3] = fmaf(a1.z, b.w, acc[6][3]);
            acc[7][0] = fmaf(a1.w, b.x, acc[7][0]); acc[7][1] = fmaf(a1.w, b.y, acc[7][1]);
            acc[7][2] = fmaf(a1.w, b.z, acc[7][2]); acc[7][3] = fmaf(a1.w, b.w, acc[7][3]);
        }
    }
    #pragma unroll
    for (int m = 0; m < 8; m++) {
        int r = row0 + ty * 8 + m;
        if (r < M) {
            float dv = dinv[r];
            uint32_t p0 = pk_bf16(acc[m][0] * dv, acc[m][1] * dv);
            uint32_t p1 = pk_bf16(acc[m][2] * dv, acc[m][3] * dv);
            // bf16 row-major: row r is 64 uints; thread covers cols 4*tx..4*tx+3 = 2 uints
            uint2 o = make_uint2(p0, p1);
            *(uint2*)&Hs[(size_t)r * 64 + tx * 2] = o;
        }
    }
}

// ---------------------------------------------------------------------------
// Aggregation layer 1: wave per node, one uint (2 bf16) per lane.
// a1[v] = relu(dinv[v]*(sum_{s in N(v)} h1s[s] + h1s[v]) + b1)   [h1s pre-scaled]
// 4-way unrolled gather for MLP (memory-level parallelism).
// ---------------------------------------------------------------------------
__global__ __launch_bounds__(256) void k_agg1(const uint32_t* __restrict__ hs,
                                              const int* __restrict__ offs,
                                              const int* __restrict__ cnt,
                                              const float* __restrict__ dinv,
                                              const int* __restrict__ ssrc,
                                              const float* __restrict__ b1,
                                              float* __restrict__ a1, int N) {
    int wid = (blockIdx.x * 256 + threadIdx.x) >> 6;
    int lane = threadIdx.x & 63;
    if (wid >= N) return;
    float dv = dinv[wid];
    uint32_t self = hs[(size_t)wid * 64 + lane];
    float ax = bl(self), ay = bh(self);
    int beg = offs[wid], n = cnt[wid];
    const int* sp = ssrc + beg;
    int j = 0;
    int n4 = n & ~3;
    for (; j < n4; j += 4) {
        int s0 = sp[j], s1 = sp[j + 1], s2 = sp[j + 2], s3 = sp[j + 3];
        uint32_t u0 = hs[(size_t)s0 * 64 + lane];
        uint32_t u1 = hs[(size_t)s1 * 64 + lane];
        uint32_t u2 = hs[(size_t)s2 * 64 + lane];
        uint32_t u3 = hs[(size_t)s3 * 64 + lane];
        ax += bl(u0); ay += bh(u0);
        ax += bl(u1); ay += bh(u1);
        ax += bl(u2); ay += bh(u2);
        ax += bl(u3); ay += bh(u3);
    }
    for (; j < n; j++) {
        int s = sp[j];
        uint32_t u = hs[(size_t)s * 64 + lane];
        ax += bl(u); ay += bh(u);
    }
    float2 bb = ((const float2*)b1)[lane];
    float ox = fmaxf(fmaf(ax, dv, bb.x), 0.f);
    float oy = fmaxf(fmaf(ay, dv, bb.y), 0.f);
    ((float2*)a1)[(size_t)wid * 64 + lane] = make_float2(ox, oy);
}

// ---------------------------------------------------------------------------
// GEMM2: h2s[100000,8] = (a1[100000,128] @ W2[128,8]) * dinv[node]
// W2 in LDS; thread = (node, feat); 32 nodes per 256-thread block.
// ---------------------------------------------------------------------------
__global__ __launch_bounds__(256) void k_gemm2(const float* __restrict__ a1,
                                               const float* __restrict__ W2,
                                               const float* __restrict__ dinv,
                                               float* __restrict__ h2s, int N) {
    __shared__ float w[HID * OUT_F];
    int t = threadIdx.x;
    for (int i = t; i < HID * OUT_F; i += 256) w[i] = W2[i];
    __syncthreads();
    int node = blockIdx.x * 32 + (t >> 3);
    int f = t & 7;
    if (node >= N) return;
    const float* ar = a1 + (size_t)node * HID;
    float acc = 0.f;
    #pragma unroll 8
    for (int k = 0; k < HID; k++) acc = fmaf(ar[k], w[k * OUT_F + f], acc);
    h2s[(size_t)node * OUT_F + f] = acc * dinv[node];
}

// ---------------------------------------------------------------------------
// Aggregation layer 2 + bias + log_softmax, fused. Wave per node:
// lane = (edge_group 0..7) * 8 + feat 0..7. h2s pre-scaled by dinv[src].
// ---------------------------------------------------------------------------
__global__ __launch_bounds__(256) void k_agg2(const float* __restrict__ h2s,
                                              const int* __restrict__ offs,
                                              const int* __restrict__ cnt,
                                              const float* __restrict__ dinv,
                                              const int* __restrict__ ssrc,
                                              const float* __restrict__ b2,
                                              float* __restrict__ out, int N) {
    int wid = (blockIdx.x * 256 + threadIdx.x) >> 6;
    int lane = threadIdx.x & 63;
    if (wid >= N) return;
    int f = lane & 7, g = lane >> 3;
    float dv = dinv[wid];
    int beg = offs[wid], n = cnt[wid];
    float acc = 0.f;
    for (int j = g; j < n; j += 8) {
        int s = ssrc[beg + j];
        acc += h2s[(size_t)s * OUT_F + f];
    }
    acc += __shfl_xor(acc, 8);
    acc += __shfl_xor(acc, 16);
    acc += __shfl_xor(acc, 32);
    // self-loop (pre-scaled) + final norm + bias
    acc += h2s[(size_t)wid * OUT_F + f];
    acc = fmaf(acc, dv, b2[f]);
    // log_softmax over the 8 feats (lanes differing in bits 0..2)
    float m = acc;
    m = fmaxf(m, __shfl_xor(m, 1));
    m = fmaxf(m, __shfl_xor(m, 2));
    m = fmaxf(m, __shfl_xor(m, 4));
    float e = expf(acc - m);
    float ssum = e;
    ssum += __shfl_xor(ssum, 1);
    ssum += __shfl_xor(ssum, 2);
    ssum += __shfl_xor(ssum, 4);
    float res = acc - m - logf(ssum);
    if (lane < 8) out[(size_t)wid * OUT_F + lane] = res;
}

// ---------------------------------------------------------------------------
extern "C" void kernel_launch(void* const* d_in, const int* in_sizes, int n_in,
                              void* d_out, int out_size, void* d_ws, size_t ws_size,
                              hipStream_t stream) {
    const float* x   = (const float*)d_in[0];
    const int*   ei  = (const int*)d_in[1];     // [2, E] flat: src then dst
    const float* W1  = (const float*)d_in[2];
    const float* b1  = (const float*)d_in[3];
    const float* W2  = (const float*)d_in[4];
    const float* b2  = (const float*)d_in[5];
    float* out = (float*)d_out;

    const int N = N_NODES, E = N_EDGES;
    const int* src = ei;
    const int* dst = ei + E;

    char* p = (char*)d_ws;
    auto carve = [&](size_t bytes) -> void* {
        void* r = (void*)p;
        p += (bytes + 511) & ~(size_t)511;
        return r;
    };
    int*      cnt    = (int*)carve((size_t)N * 4);
    int*      offs   = (int*)carve((size_t)N * 4);
    int*      cursor = (int*)carve((size_t)N * 4);
    float*    dinv   = (float*)carve((size_t)N * 4);
    int*      total  = (int*)carve(4);
    int*      ssrc   = (int*)carve((size_t)E * 4);
    uint32_t* h1s    = (uint32_t*)carve((size_t)N * 64 * 4);   // bf16 rows, 256B each
    float*    a1     = (float*)carve((size_t)N * HID * 4);
    float*    h2s    = (float*)carve((size_t)N * OUT_F * 4);

    hipMemsetAsync(cnt, 0, (size_t)N * 4, stream);
    hipMemsetAsync(total, 0, 4, stream);

    int eb = (E + 255) / 256;
    int nb = (N + 255) / 256;

    k_hist<<<eb, 256, 0, stream>>>(dst, cnt, E);
    k_alloc<<<nb, 256, 0, stream>>>(cnt, offs, cursor, dinv, total, N);
    k_scatter<<<eb, 256, 0, stream>>>(src, dst, cursor, ssrc, E);

    k_gemm1<<<(N + 63) / 64, 256, 0, stream>>>(x, W1, dinv, h1s, N);
    k_agg1<<<(N * 64 + 255) / 256, 256, 0, stream>>>(h1s, offs, cnt, dinv, ssrc, b1, a1, N);
    k_gemm2<<<(N + 31) / 32, 256, 0, stream>>>(a1, W2, dinv, h2s, N);
    k_agg2<<<(N * 64 + 255) / 256, 256, 0, stream>>>(h2s, offs, cnt, dinv, ssrc, b2, out, N);
}

// Round 3
// 535.112 us; speedup vs baseline: 1.9064x; 1.4773x over previous
//
#include <hip/hip_runtime.h>
#include <hip/hip_bf16.h>
#include <stdint.h>

#define N_NODES 100000
#define N_EDGES 3200000
#define IN_F 256
#define HID 128
#define OUT_F 8

#define NB   391        // node buckets of 256: ceil(100000/256)
#define PASS 12288      // edges staged per k_part block
#define CAP  10240      // k_csr LDS stage capacity (mean bucket = 8184, +20 sigma safe)

// bf16 pack/unpack helpers (RNE rounding; finite values only)
__device__ __forceinline__ uint32_t pk_bf16(float a, float b) {
    uint32_t ua = __float_as_uint(a);
    uint32_t ub = __float_as_uint(b);
    ua = (ua + 0x7fff + ((ua >> 16) & 1)) >> 16;
    ub = (ub + 0x7fff + ((ub >> 16) & 1)) & 0xffff0000u;
    return ua | ub;
}
__device__ __forceinline__ float bl(uint32_t u) { return __uint_as_float(u << 16); }
__device__ __forceinline__ float bh(uint32_t u) { return __uint_as_float(u & 0xffff0000u); }

// ---------------------------------------------------------------------------
// Bucket histogram: LDS-aggregated, flushed to 256B-strided global counters
// ---------------------------------------------------------------------------
__global__ __launch_bounds__(256) void k_bhist(const int* __restrict__ dst,
                                               int* __restrict__ gcnt, int E) {
    __shared__ int lb[NB];
    for (int i = threadIdx.x; i < NB; i += 256) lb[i] = 0;
    __syncthreads();
    int stride = gridDim.x * 256;
    for (int e = blockIdx.x * 256 + threadIdx.x; e < E; e += stride)
        atomicAdd(&lb[dst[e] >> 8], 1);
    __syncthreads();
    for (int i = threadIdx.x; i < NB; i += 256) {
        int c = lb[i];
        if (c) atomicAdd(&gcnt[i * 64], c);
    }
}

// Exclusive scan of NB bucket counts -> bbase[0..NB] (bbase[NB]=E), init cursors
__global__ __launch_bounds__(512) void k_bscan(const int* __restrict__ gcnt,
                                               int* __restrict__ bbase,
                                               int* __restrict__ gcur) {
    __shared__ int sc[512];
    int tid = threadIdx.x;
    int v = (tid < NB) ? gcnt[tid * 64] : 0;
    sc[tid] = v;
    __syncthreads();
    for (int d = 1; d < 512; d <<= 1) {
        int t = (tid >= d) ? sc[tid - d] : 0;
        __syncthreads();
        sc[tid] += t;
        __syncthreads();
    }
    int excl = sc[tid] - v;
    if (tid <= NB) bbase[tid] = excl;
    if (tid < NB) gcur[tid * 64] = excl;
}

// ---------------------------------------------------------------------------
// Partition edges into bucket-contiguous regions. LDS-staged so global writes
// are bucket-major runs (~31 consecutive words) instead of isolated 4B stores.
// Packed entry: bits [0,17) = src, bits [17,25) = dst & 255.
// ---------------------------------------------------------------------------
__global__ __launch_bounds__(256) void k_part(const int* __restrict__ src,
                                              const int* __restrict__ dst,
                                              int* __restrict__ gcur,
                                              uint32_t* __restrict__ epk, int E) {
    __shared__ int lcnt[NB], loff[NB], ladj[NB], lcur[NB];
    __shared__ int sc[512];
    __shared__ uint32_t stage[PASS];
    int tid = threadIdx.x;
    int e0 = blockIdx.x * PASS;

    for (int i = tid; i < NB; i += 256) { lcnt[i] = 0; lcur[i] = 0; }
    __syncthreads();
    // pass 1: count
    for (int i = tid; i < PASS; i += 256) {
        int e = e0 + i;
        if (e < E) atomicAdd(&lcnt[dst[e] >> 8], 1);
    }
    __syncthreads();
    // scan 512 slots with 256 threads (2 slots each), Hillis-Steele
    int v0 = (tid < NB) ? lcnt[tid] : 0;
    int v1 = (256 + tid < NB) ? lcnt[256 + tid] : 0;
    sc[tid] = v0; sc[256 + tid] = v1;
    __syncthreads();
    for (int d = 1; d < 512; d <<= 1) {
        int t0 = (tid >= d) ? sc[tid - d] : 0;
        int t1 = (256 + tid >= d) ? sc[256 + tid - d] : 0;
        __syncthreads();
        sc[tid] += t0; sc[256 + tid] += t1;
        __syncthreads();
    }
    if (tid < NB) loff[tid] = sc[tid] - v0;
    if (256 + tid < NB) loff[256 + tid] = sc[256 + tid] - v1;
    __syncthreads();
    // reserve global ranges (one atomic per non-empty bucket per block)
    for (int b = tid; b < NB; b += 256) {
        int len = lcnt[b];
        if (len > 0) ladj[b] = atomicAdd(&gcur[b * 64], len);
    }
    __syncthreads();
    // pass 2: scatter into LDS stage (bucket-major layout)
    for (int i = tid; i < PASS; i += 256) {
        int e = e0 + i;
        if (e < E) {
            int d = dst[e];
            int b = d >> 8;
            int r = atomicAdd(&lcur[b], 1);
            stage[loff[b] + r] = (uint32_t)src[e] | ((uint32_t)(d & 255) << 17);
        }
    }
    __syncthreads();
    // flush: wave per bucket -> contiguous runs
    int wv = tid >> 6, ln = tid & 63;
    for (int b = wv; b < NB; b += 4) {
        int len = lcnt[b], lo = loff[b], gb = ladj[b];
        for (int j = ln; j < len; j += 64) epk[gb + j] = stage[lo + j];
    }
}

// ---------------------------------------------------------------------------
// Per-bucket CSR: per-node counts+prefix in LDS, scatter src ids to LDS stage,
// coalesced copy out. Emits offs/cnt/dinv (replaces separate hist/alloc).
// ---------------------------------------------------------------------------
__global__ __launch_bounds__(256) void k_csr(const uint32_t* __restrict__ epk,
                                             const int* __restrict__ bbase,
                                             int* __restrict__ offs,
                                             int* __restrict__ cnt,
                                             float* __restrict__ dinv,
                                             int* __restrict__ ssrc, int N) {
    __shared__ int lcnt[256], lcur[256], loff[256];
    __shared__ uint32_t stage[CAP];
    int tid = threadIdx.x, b = blockIdx.x;
    int base = bbase[b], m = bbase[b + 1] - base;

    lcnt[tid] = 0;
    __syncthreads();
    for (int i = tid; i < m; i += 256)
        atomicAdd(&lcnt[(epk[base + i] >> 17) & 255], 1);
    __syncthreads();
    int v = lcnt[tid];
    loff[tid] = v;
    __syncthreads();
    for (int d = 1; d < 256; d <<= 1) {
        int t = (tid >= d) ? loff[tid - d] : 0;
        __syncthreads();
        loff[tid] += t;
        __syncthreads();
    }
    int excl = loff[tid] - v;
    __syncthreads();
    loff[tid] = excl;
    lcur[tid] = 0;
    int node = b * 256 + tid;
    if (node < N) {
        offs[node] = base + excl;
        cnt[node] = v;
        dinv[node] = rsqrtf((float)(v + 1));
    }
    __syncthreads();
    if (m <= CAP) {
        for (int i = tid; i < m; i += 256) {
            uint32_t u = epk[base + i];
            int ld = (u >> 17) & 255;
            int r = atomicAdd(&lcur[ld], 1);
            stage[loff[ld] + r] = u & 0x1FFFF;
        }
        __syncthreads();
        for (int i = tid; i < m; i += 256) ssrc[base + i] = (int)stage[i];
    } else {
        // statistically unreachable fallback; correctness guard
        for (int i = tid; i < m; i += 256) {
            uint32_t u = epk[base + i];
            int ld = (u >> 17) & 255;
            int r = atomicAdd(&lcur[ld], 1);
            ssrc[base + loff[ld] + r] = (int)(u & 0x1FFFF);
        }
    }
}

// ---------------------------------------------------------------------------
// GEMM1: H1s[100000,128](bf16) = (X @ W1) * dinv[row]
// ---------------------------------------------------------------------------
__global__ __launch_bounds__(256) void k_gemm1(const float* __restrict__ X,
                                               const float* __restrict__ W,
                                               const float* __restrict__ dinv,
                                               uint32_t* __restrict__ Hs, int M) {
    __shared__ float xs[16][68];
    __shared__ float ws[16 * 128];
    int t  = threadIdx.x;
    int tx = t & 31;
    int ty = t >> 5;
    int row0 = blockIdx.x * 64;

    int lrow = t >> 2;
    int lk   = (t & 3) * 4;
    int grow = row0 + lrow;
    if (grow >= M) grow = M - 1;
    const float* xrow = X + (size_t)grow * IN_F;

    float acc[8][4];
    #pragma unroll
    for (int m = 0; m < 8; m++)
        #pragma unroll
        for (int n = 0; n < 4; n++) acc[m][n] = 0.f;

    for (int k0 = 0; k0 < IN_F; k0 += 16) {
        float4 xv = *(const float4*)(xrow + k0 + lk);
        int kk0 = t >> 5, c4 = t & 31;
        float4 wv0 = *(const float4*)(W + (size_t)(k0 + kk0) * HID + c4 * 4);
        float4 wv1 = *(const float4*)(W + (size_t)(k0 + 8 + kk0) * HID + c4 * 4);
        __syncthreads();
        xs[lk + 0][lrow] = xv.x;
        xs[lk + 1][lrow] = xv.y;
        xs[lk + 2][lrow] = xv.z;
        xs[lk + 3][lrow] = xv.w;
        *(float4*)&ws[(kk0) * HID + c4 * 4]     = wv0;
        *(float4*)&ws[(kk0 + 8) * HID + c4 * 4] = wv1;
        __syncthreads();
        const float4* wsf4 = (const float4*)ws;
        #pragma unroll
        for (int kk = 0; kk < 16; kk++) {
            float4 b  = wsf4[kk * 32 + tx];
            float4 a0 = *(const float4*)&xs[kk][ty * 8];
            float4 a1 = *(const float4*)&xs[kk][ty * 8 + 4];
            acc[0][0] = fmaf(a0.x, b.x, acc[0][0]); acc[0][1] = fmaf(a0.x, b.y, acc[0][1]);
            acc[0][2] = fmaf(a0.x, b.z, acc[0][2]); acc[0][3] = fmaf(a0.x, b.w, acc[0][3]);
            acc[1][0] = fmaf(a0.y, b.x, acc[1][0]); acc[1][1] = fmaf(a0.y, b.y, acc[1][1]);
            acc[1][2] = fmaf(a0.y, b.z, acc[1][2]); acc[1][3] = fmaf(a0.y, b.w, acc[1][3]);
            acc[2][0] = fmaf(a0.z, b.x, acc[2][0]); acc[2][1] = fmaf(a0.z, b.y, acc[2][1]);
            acc[2][2] = fmaf(a0.z, b.z, acc[2][2]); acc[2][3] = fmaf(a0.z, b.w, acc[2][3]);
            acc[3][0] = fmaf(a0.w, b.x, acc[3][0]); acc[3][1] = fmaf(a0.w, b.y, acc[3][1]);
            acc[3][2] = fmaf(a0.w, b.z, acc[3][2]); acc[3][3] = fmaf(a0.w, b.w, acc[3][3]);
            acc[4][0] = fmaf(a1.x, b.x, acc[4][0]); acc[4][1] = fmaf(a1.x, b.y, acc[4][1]);
            acc[4][2] = fmaf(a1.x, b.z, acc[4][2]); acc[4][3] = fmaf(a1.x, b.w, acc[4][3]);
            acc[5][0] = fmaf(a1.y, b.x, acc[5][0]); acc[5][1] = fmaf(a1.y, b.y, acc[5][1]);
            acc[5][2] = fmaf(a1.y, b.z, acc[5][2]); acc[5][3] = fmaf(a1.y, b.w, acc[5][3]);
            acc[6][0] = fmaf(a1.z, b.x, acc[6][0]); acc[6][1] = fmaf(a1.z, b.y, acc[6][1]);
            acc[6][2] = fmaf(a1.z, b.z, acc[6][2]); acc[6][3] = fmaf(a1.z, b.w, acc[6][3]);
            acc[7][0] = fmaf(a1.w, b.x, acc[7][0]); acc[7][1] = fmaf(a1.w, b.y, acc[7][1]);
            acc[7][2] = fmaf(a1.w, b.z, acc[7][2]); acc[7][3] = fmaf(a1.w, b.w, acc[7][3]);
        }
    }
    #pragma unroll
    for (int m = 0; m < 8; m++) {
        int r = row0 + ty * 8 + m;
        if (r < M) {
            float dv = dinv[r];
            uint32_t p0 = pk_bf16(acc[m][0] * dv, acc[m][1] * dv);
            uint32_t p1 = pk_bf16(acc[m][2] * dv, acc[m][3] * dv);
            uint2 o = make_uint2(p0, p1);
            *(uint2*)&Hs[(size_t)r * 64 + tx * 2] = o;
        }
    }
}

// ---------------------------------------------------------------------------
// Aggregation layer 1: wave per node, one uint (2 bf16) per lane.
// ---------------------------------------------------------------------------
__global__ __launch_bounds__(256) void k_agg1(const uint32_t* __restrict__ hs,
                                              const int* __restrict__ offs,
                                              const int* __restrict__ cnt,
                                              const float* __restrict__ dinv,
                                              const int* __restrict__ ssrc,
                                              const float* __restrict__ b1,
                                              float* __restrict__ a1, int N) {
    int wid = (blockIdx.x * 256 + threadIdx.x) >> 6;
    int lane = threadIdx.x & 63;
    if (wid >= N) return;
    float dv = dinv[wid];
    uint32_t self = hs[(size_t)wid * 64 + lane];
    float ax = bl(self), ay = bh(self);
    int beg = offs[wid], n = cnt[wid];
    const int* sp = ssrc + beg;
    int j = 0;
    int n4 = n & ~3;
    for (; j < n4; j += 4) {
        int s0 = sp[j], s1 = sp[j + 1], s2 = sp[j + 2], s3 = sp[j + 3];
        uint32_t u0 = hs[(size_t)s0 * 64 + lane];
        uint32_t u1 = hs[(size_t)s1 * 64 + lane];
        uint32_t u2 = hs[(size_t)s2 * 64 + lane];
        uint32_t u3 = hs[(size_t)s3 * 64 + lane];
        ax += bl(u0); ay += bh(u0);
        ax += bl(u1); ay += bh(u1);
        ax += bl(u2); ay += bh(u2);
        ax += bl(u3); ay += bh(u3);
    }
    for (; j < n; j++) {
        int s = sp[j];
        uint32_t u = hs[(size_t)s * 64 + lane];
        ax += bl(u); ay += bh(u);
    }
    float2 bb = ((const float2*)b1)[lane];
    float ox = fmaxf(fmaf(ax, dv, bb.x), 0.f);
    float oy = fmaxf(fmaf(ay, dv, bb.y), 0.f);
    ((float2*)a1)[(size_t)wid * 64 + lane] = make_float2(ox, oy);
}

// ---------------------------------------------------------------------------
// GEMM2: h2s[100000,8] = (a1 @ W2) * dinv[node]
// ---------------------------------------------------------------------------
__global__ __launch_bounds__(256) void k_gemm2(const float* __restrict__ a1,
                                               const float* __restrict__ W2,
                                               const float* __restrict__ dinv,
                                               float* __restrict__ h2s, int N) {
    __shared__ float w[HID * OUT_F];
    int t = threadIdx.x;
    for (int i = t; i < HID * OUT_F; i += 256) w[i] = W2[i];
    __syncthreads();
    int node = blockIdx.x * 32 + (t >> 3);
    int f = t & 7;
    if (node >= N) return;
    const float* ar = a1 + (size_t)node * HID;
    float acc = 0.f;
    #pragma unroll 8
    for (int k = 0; k < HID; k++) acc = fmaf(ar[k], w[k * OUT_F + f], acc);
    h2s[(size_t)node * OUT_F + f] = acc * dinv[node];
}

// ---------------------------------------------------------------------------
// Aggregation layer 2 + bias + log_softmax, fused.
// ---------------------------------------------------------------------------
__global__ __launch_bounds__(256) void k_agg2(const float* __restrict__ h2s,
                                              const int* __restrict__ offs,
                                              const int* __restrict__ cnt,
                                              const float* __restrict__ dinv,
                                              const int* __restrict__ ssrc,
                                              const float* __restrict__ b2,
                                              float* __restrict__ out, int N) {
    int wid = (blockIdx.x * 256 + threadIdx.x) >> 6;
    int lane = threadIdx.x & 63;
    if (wid >= N) return;
    int f = lane & 7, g = lane >> 3;
    float dv = dinv[wid];
    int beg = offs[wid], n = cnt[wid];
    float acc = 0.f;
    for (int j = g; j < n; j += 8) {
        int s = ssrc[beg + j];
        acc += h2s[(size_t)s * OUT_F + f];
    }
    acc += __shfl_xor(acc, 8);
    acc += __shfl_xor(acc, 16);
    acc += __shfl_xor(acc, 32);
    acc += h2s[(size_t)wid * OUT_F + f];
    acc = fmaf(acc, dv, b2[f]);
    float m = acc;
    m = fmaxf(m, __shfl_xor(m, 1));
    m = fmaxf(m, __shfl_xor(m, 2));
    m = fmaxf(m, __shfl_xor(m, 4));
    float e = expf(acc - m);
    float ssum = e;
    ssum += __shfl_xor(ssum, 1);
    ssum += __shfl_xor(ssum, 2);
    ssum += __shfl_xor(ssum, 4);
    float res = acc - m - logf(ssum);
    if (lane < 8) out[(size_t)wid * OUT_F + lane] = res;
}

// ---------------------------------------------------------------------------
extern "C" void kernel_launch(void* const* d_in, const int* in_sizes, int n_in,
                              void* d_out, int out_size, void* d_ws, size_t ws_size,
                              hipStream_t stream) {
    const float* x   = (const float*)d_in[0];
    const int*   ei  = (const int*)d_in[1];     // [2, E] flat: src then dst
    const float* W1  = (const float*)d_in[2];
    const float* b1  = (const float*)d_in[3];
    const float* W2  = (const float*)d_in[4];
    const float* b2  = (const float*)d_in[5];
    float* out = (float*)d_out;

    const int N = N_NODES, E = N_EDGES;
    const int* src = ei;
    const int* dst = ei + E;

    char* p = (char*)d_ws;
    auto carve = [&](size_t bytes) -> void* {
        void* r = (void*)p;
        p += (bytes + 511) & ~(size_t)511;
        return r;
    };
    int*      gcnt  = (int*)carve((size_t)NB * 64 * 4);   // 256B-strided counters
    int*      gcur  = (int*)carve((size_t)NB * 64 * 4);   // 256B-strided cursors
    int*      bbase = (int*)carve((size_t)(NB + 1) * 4);
    uint32_t* epk   = (uint32_t*)carve((size_t)E * 4);
    int*      offs  = (int*)carve((size_t)N * 4);
    int*      cnt   = (int*)carve((size_t)N * 4);
    float*    dinv  = (float*)carve((size_t)N * 4);
    int*      ssrc  = (int*)carve((size_t)E * 4);
    uint32_t* h1s   = (uint32_t*)carve((size_t)N * 64 * 4);
    float*    a1    = (float*)carve((size_t)N * HID * 4);
    float*    h2s   = (float*)carve((size_t)N * OUT_F * 4);

    hipMemsetAsync(gcnt, 0, (size_t)NB * 64 * 4, stream);

    k_bhist<<<512, 256, 0, stream>>>(dst, gcnt, E);
    k_bscan<<<1, 512, 0, stream>>>(gcnt, bbase, gcur);
    k_part<<<(E + PASS - 1) / PASS, 256, 0, stream>>>(src, dst, gcur, epk, E);
    k_csr<<<NB, 256, 0, stream>>>(epk, bbase, offs, cnt, dinv, ssrc, N);

    k_gemm1<<<(N + 63) / 64, 256, 0, stream>>>(x, W1, dinv, h1s, N);
    k_agg1<<<(N * 64 + 255) / 256, 256, 0, stream>>>(h1s, offs, cnt, dinv, ssrc, b1, a1, N);
    k_gemm2<<<(N + 31) / 32, 256, 0, stream>>>(a1, W2, dinv, h2s, N);
    k_agg2<<<(N * 64 + 255) / 256, 256, 0, stream>>>(h2s, offs, cnt, dinv, ssrc, b2, out, N);
}

// Round 4
// 436.981 us; speedup vs baseline: 2.3345x; 1.2246x over previous
//
#include <hip/hip_runtime.h>
#include <hip/hip_bf16.h>
#include <stdint.h>

#define N_NODES 100000
#define N_EDGES 3200000
#define IN_F 256
#define HID 128
#define OUT_F 8

#define NB   391        // node buckets of 256
#define PASS 12288      // edges staged per k_part block
#define CAP  10240      // k_csr LDS stage capacity

typedef short short8 __attribute__((ext_vector_type(8)));
typedef float f32x4 __attribute__((ext_vector_type(4)));
typedef float f32x2 __attribute__((ext_vector_type(2)));

// bf16 pack/unpack helpers (RNE)
__device__ __forceinline__ uint32_t pk_bf16(float a, float b) {
    uint32_t ua = __float_as_uint(a);
    uint32_t ub = __float_as_uint(b);
    ua = (ua + 0x7fff + ((ua >> 16) & 1)) >> 16;
    ub = (ub + 0x7fff + ((ub >> 16) & 1)) & 0xffff0000u;
    return ua | ub;
}
__device__ __forceinline__ float bl(uint32_t u) { return __uint_as_float(u << 16); }
__device__ __forceinline__ float bh(uint32_t u) { return __uint_as_float(u & 0xffff0000u); }

// fp8 e4m3 decode: 4 fp8 in a uint -> 4 floats (HW converter)
__device__ __forceinline__ void dec4(uint32_t u, float& a, float& b, float& c, float& d) {
    f32x2 lo = __builtin_amdgcn_cvt_pk_f32_fp8(u, false);
    f32x2 hi = __builtin_amdgcn_cvt_pk_f32_fp8(u, true);
    a = lo[0]; b = lo[1]; c = hi[0]; d = hi[1];
}

// ---------------------------------------------------------------------------
// Bucket histogram (LDS-aggregated, int4 edge reads)
// ---------------------------------------------------------------------------
__global__ __launch_bounds__(256) void k_bhist(const int* __restrict__ dst,
                                               int* __restrict__ gcnt, int E) {
    __shared__ int lb[NB];
    for (int i = threadIdx.x; i < NB; i += 256) lb[i] = 0;
    __syncthreads();
    int stride = gridDim.x * 256;
    const int4* d4 = (const int4*)dst;
    for (int e = blockIdx.x * 256 + threadIdx.x; e < E / 4; e += stride) {
        int4 d = d4[e];
        atomicAdd(&lb[d.x >> 8], 1);
        atomicAdd(&lb[d.y >> 8], 1);
        atomicAdd(&lb[d.z >> 8], 1);
        atomicAdd(&lb[d.w >> 8], 1);
    }
    __syncthreads();
    for (int i = threadIdx.x; i < NB; i += 256) {
        int c = lb[i];
        if (c) atomicAdd(&gcnt[i * 64], c);
    }
}

__global__ __launch_bounds__(512) void k_bscan(const int* __restrict__ gcnt,
                                               int* __restrict__ bbase,
                                               int* __restrict__ gcur) {
    __shared__ int sc[512];
    int tid = threadIdx.x;
    int v = (tid < NB) ? gcnt[tid * 64] : 0;
    sc[tid] = v;
    __syncthreads();
    for (int d = 1; d < 512; d <<= 1) {
        int t = (tid >= d) ? sc[tid - d] : 0;
        __syncthreads();
        sc[tid] += t;
        __syncthreads();
    }
    int excl = sc[tid] - v;
    if (tid <= NB) bbase[tid] = excl;
    if (tid < NB) gcur[tid * 64] = excl;
}

// ---------------------------------------------------------------------------
// Partition edges into bucket-contiguous regions (LDS-staged flush)
// ---------------------------------------------------------------------------
__global__ __launch_bounds__(256) void k_part(const int* __restrict__ src,
                                              const int* __restrict__ dst,
                                              int* __restrict__ gcur,
                                              uint32_t* __restrict__ epk, int E) {
    __shared__ int lcnt[NB], loff[NB], ladj[NB], lcur[NB];
    __shared__ int sc[512];
    __shared__ uint32_t stage[PASS];
    int tid = threadIdx.x;
    int e0 = blockIdx.x * PASS;

    for (int i = tid; i < NB; i += 256) { lcnt[i] = 0; lcur[i] = 0; }
    __syncthreads();
    for (int i = tid; i < PASS; i += 256) {
        int e = e0 + i;
        if (e < E) atomicAdd(&lcnt[dst[e] >> 8], 1);
    }
    __syncthreads();
    int v0 = (tid < NB) ? lcnt[tid] : 0;
    int v1 = (256 + tid < NB) ? lcnt[256 + tid] : 0;
    sc[tid] = v0; sc[256 + tid] = v1;
    __syncthreads();
    for (int d = 1; d < 512; d <<= 1) {
        int t0 = (tid >= d) ? sc[tid - d] : 0;
        int t1 = (256 + tid >= d) ? sc[256 + tid - d] : 0;
        __syncthreads();
        sc[tid] += t0; sc[256 + tid] += t1;
        __syncthreads();
    }
    if (tid < NB) loff[tid] = sc[tid] - v0;
    if (256 + tid < NB) loff[256 + tid] = sc[256 + tid] - v1;
    __syncthreads();
    for (int b = tid; b < NB; b += 256) {
        int len = lcnt[b];
        if (len > 0) ladj[b] = atomicAdd(&gcur[b * 64], len);
    }
    __syncthreads();
    for (int i = tid; i < PASS; i += 256) {
        int e = e0 + i;
        if (e < E) {
            int d = dst[e];
            int b = d >> 8;
            int r = atomicAdd(&lcur[b], 1);
            stage[loff[b] + r] = (uint32_t)src[e] | ((uint32_t)(d & 255) << 17);
        }
    }
    __syncthreads();
    int wv = tid >> 6, ln = tid & 63;
    for (int b = wv; b < NB; b += 4) {
        int len = lcnt[b], lo = loff[b], gb = ladj[b];
        for (int j = ln; j < len; j += 64) epk[gb + j] = stage[lo + j];
    }
}

// ---------------------------------------------------------------------------
// Per-bucket CSR finalize: offs/cnt/dinv + node-sorted ssrc
// ---------------------------------------------------------------------------
__global__ __launch_bounds__(256) void k_csr(const uint32_t* __restrict__ epk,
                                             const int* __restrict__ bbase,
                                             int* __restrict__ offs,
                                             int* __restrict__ cnt,
                                             float* __restrict__ dinv,
                                             int* __restrict__ ssrc, int N) {
    __shared__ int lcnt[256], lcur[256], loff[256];
    __shared__ uint32_t stage[CAP];
    int tid = threadIdx.x, b = blockIdx.x;
    int base = bbase[b], m = bbase[b + 1] - base;

    lcnt[tid] = 0;
    __syncthreads();
    for (int i = tid; i < m; i += 256)
        atomicAdd(&lcnt[(epk[base + i] >> 17) & 255], 1);
    __syncthreads();
    int v = lcnt[tid];
    loff[tid] = v;
    __syncthreads();
    for (int d = 1; d < 256; d <<= 1) {
        int t = (tid >= d) ? loff[tid - d] : 0;
        __syncthreads();
        loff[tid] += t;
        __syncthreads();
    }
    int excl = loff[tid] - v;
    __syncthreads();
    loff[tid] = excl;
    lcur[tid] = 0;
    int node = b * 256 + tid;
    if (node < N) {
        offs[node] = base + excl;
        cnt[node] = v;
        dinv[node] = rsqrtf((float)(v + 1));
    }
    __syncthreads();
    if (m <= CAP) {
        for (int i = tid; i < m; i += 256) {
            uint32_t u = epk[base + i];
            int ld = (u >> 17) & 255;
            int r = atomicAdd(&lcur[ld], 1);
            stage[loff[ld] + r] = u & 0x1FFFF;
        }
        __syncthreads();
        for (int i = tid; i < m; i += 256) ssrc[base + i] = (int)stage[i];
    } else {
        for (int i = tid; i < m; i += 256) {
            uint32_t u = epk[base + i];
            int ld = (u >> 17) & 255;
            int r = atomicAdd(&lcur[ld], 1);
            ssrc[base + loff[ld] + r] = (int)(u & 0x1FFFF);
        }
    }
}

// ---------------------------------------------------------------------------
// W1 [256][128] fp32 -> W1bf [128][256] bf16 (transposed, n-major)
// ---------------------------------------------------------------------------
__global__ __launch_bounds__(256) void k_wcast(const float* __restrict__ W1,
                                               ushort* __restrict__ Wbf) {
    __shared__ ushort T[128][33];
    int t = threadIdx.x;
    int k0 = blockIdx.x * 32;
    for (int idx = t; idx < 32 * 128; idx += 256) {
        int k = idx >> 7, n = idx & 127;
        uint32_t uv = __float_as_uint(W1[(size_t)(k0 + k) * HID + n]);
        uv = (uv + 0x7fff + ((uv >> 16) & 1)) >> 16;
        T[n][k] = (ushort)uv;
    }
    __syncthreads();
    for (int idx = t; idx < 32 * 128; idx += 256) {
        int n = idx >> 5, k = idx & 31;
        Wbf[(size_t)n * IN_F + k0 + k] = T[n][k];
    }
}

// ---------------------------------------------------------------------------
// GEMM1 (MFMA bf16): Hs8[100000][128](fp8 e4m3) = (X @ W1) * dinv[row]
// Block: 64 rows x 128 cols; 4 waves, each 16 rows x 128 cols.
// A/B tiles in LDS, row stride 40 bf16. Epilogue: dinv-scale, LDS round-trip
// (C-layout -> row-major), HW fp8 pack, coalesced uint2 stores.
// ---------------------------------------------------------------------------
__global__ __launch_bounds__(256) void k_gemm1(const float* __restrict__ X,
                                               const ushort* __restrict__ Wbf,
                                               const float* __restrict__ dinv,
                                               uint32_t* __restrict__ Hs8, int M) {
    __shared__ uint32_t As[64 * 20];    // 64 rows x 40 bf16
    __shared__ uint32_t Bs[128 * 20];   // 128 n-rows x 40 bf16
    __shared__ float st[4][16 * 132];   // per-wave epilogue stage
    int t = threadIdx.x;
    int lane = t & 63, w = t >> 6;
    int q = lane >> 4, c16 = lane & 15;
    int row0 = blockIdx.x * 64;

    int ar = t >> 2, a4 = (t & 3);
    int grow = row0 + ar; if (grow >= M) grow = M - 1;
    const float* xrow = X + (size_t)grow * IN_F;
    int bn = t >> 1, b1h = (t & 1);
    const ushort* wrow = Wbf + (size_t)bn * IN_F;

    f32x4 acc[8];
    #pragma unroll
    for (int j = 0; j < 8; j++) acc[j] = (f32x4){0.f, 0.f, 0.f, 0.f};

    for (int kc = 0; kc < IN_F; kc += 32) {
        float4 x0 = *(const float4*)(xrow + kc + a4 * 8);
        float4 x1 = *(const float4*)(xrow + kc + a4 * 8 + 4);
        uint4 wv0 = *(const uint4*)(wrow + kc + b1h * 16);
        uint4 wv1 = *(const uint4*)(wrow + kc + b1h * 16 + 8);
        __syncthreads();
        *(uint2*)&As[ar * 20 + a4 * 4]     = make_uint2(pk_bf16(x0.x, x0.y), pk_bf16(x0.z, x0.w));
        *(uint2*)&As[ar * 20 + a4 * 4 + 2] = make_uint2(pk_bf16(x1.x, x1.y), pk_bf16(x1.z, x1.w));
        *(uint4*)&Bs[bn * 20 + b1h * 8]     = wv0;
        *(uint4*)&Bs[bn * 20 + b1h * 8 + 4] = wv1;
        __syncthreads();
        short8 af = *(const short8*)&As[(w * 16 + c16) * 20 + q * 4];
        #pragma unroll
        for (int j = 0; j < 8; j++) {
            short8 bf = *(const short8*)&Bs[(j * 16 + c16) * 20 + q * 4];
            acc[j] = __builtin_amdgcn_mfma_f32_16x16x32_bf16(af, bf, acc[j], 0, 0, 0);
        }
    }
    // epilogue
    float dv[4];
    #pragma unroll
    for (int r = 0; r < 4; r++) {
        int gr = row0 + w * 16 + q * 4 + r;
        dv[r] = (gr < M) ? dinv[gr] : 0.f;
    }
    #pragma unroll
    for (int j = 0; j < 8; j++)
        #pragma unroll
        for (int r = 0; r < 4; r++)
            st[w][(q * 4 + r) * 132 + j * 16 + c16] = acc[j][r] * dv[r];
    __syncthreads();
    #pragma unroll
    for (int p = 0; p < 4; p++) {
        int rr = p * 4 + q;
        int gr = row0 + w * 16 + rr;
        float4 v0 = *(const float4*)&st[w][rr * 132 + c16 * 8];
        float4 v1 = *(const float4*)&st[w][rr * 132 + c16 * 8 + 4];
        uint32_t lo = 0, hi = 0;
        lo = __builtin_amdgcn_cvt_pk_fp8_f32(v0.x, v0.y, lo, false);
        lo = __builtin_amdgcn_cvt_pk_fp8_f32(v0.z, v0.w, lo, true);
        hi = __builtin_amdgcn_cvt_pk_fp8_f32(v1.x, v1.y, hi, false);
        hi = __builtin_amdgcn_cvt_pk_fp8_f32(v1.z, v1.w, hi, true);
        if (gr < M) *(uint2*)&Hs8[(size_t)gr * 32 + c16 * 2] = make_uint2(lo, hi);
    }
}

// ---------------------------------------------------------------------------
// Aggregation layer 1: wave per node, fp8 rows (128B). Half-wave per edge:
// lanes 0-31 even edges, 32-63 odd edges; 4 loads in flight; shfl_xor combine.
// Output a1 as bf16 rows (256B).
// ---------------------------------------------------------------------------
__global__ __launch_bounds__(256) void k_agg1(const uint32_t* __restrict__ hs,
                                              const int* __restrict__ offs,
                                              const int* __restrict__ cnt,
                                              const float* __restrict__ dinv,
                                              const int* __restrict__ ssrc,
                                              const float* __restrict__ b1,
                                              uint32_t* __restrict__ a1, int N) {
    int wid = (blockIdx.x * 256 + threadIdx.x) >> 6;
    int lane = threadIdx.x & 63;
    if (wid >= N) return;
    int h = lane >> 5, c = lane & 31;
    float dv = dinv[wid];
    float s0f = 0.f, s1f = 0.f, s2f = 0.f, s3f = 0.f;
    if (h == 0) {
        dec4(hs[(size_t)wid * 32 + c], s0f, s1f, s2f, s3f);
    }
    int beg = offs[wid], n = cnt[wid];
    const int* sp = ssrc + beg;
    int j = h;
    for (; j + 6 < n; j += 8) {
        int e0 = sp[j], e1 = sp[j + 2], e2 = sp[j + 4], e3 = sp[j + 6];
        uint32_t u0 = hs[(size_t)e0 * 32 + c];
        uint32_t u1 = hs[(size_t)e1 * 32 + c];
        uint32_t u2 = hs[(size_t)e2 * 32 + c];
        uint32_t u3 = hs[(size_t)e3 * 32 + c];
        float x0, x1, x2, x3;
        dec4(u0, x0, x1, x2, x3); s0f += x0; s1f += x1; s2f += x2; s3f += x3;
        dec4(u1, x0, x1, x2, x3); s0f += x0; s1f += x1; s2f += x2; s3f += x3;
        dec4(u2, x0, x1, x2, x3); s0f += x0; s1f += x1; s2f += x2; s3f += x3;
        dec4(u3, x0, x1, x2, x3); s0f += x0; s1f += x1; s2f += x2; s3f += x3;
    }
    for (; j < n; j += 2) {
        uint32_t u = hs[(size_t)sp[j] * 32 + c];
        float x0, x1, x2, x3;
        dec4(u, x0, x1, x2, x3); s0f += x0; s1f += x1; s2f += x2; s3f += x3;
    }
    s0f += __shfl_xor(s0f, 32);
    s1f += __shfl_xor(s1f, 32);
    s2f += __shfl_xor(s2f, 32);
    s3f += __shfl_xor(s3f, 32);
    if (h == 0) {
        float4 bb = *(const float4*)(b1 + c * 4);
        float o0 = fmaxf(fmaf(s0f, dv, bb.x), 0.f);
        float o1 = fmaxf(fmaf(s1f, dv, bb.y), 0.f);
        float o2 = fmaxf(fmaf(s2f, dv, bb.z), 0.f);
        float o3 = fmaxf(fmaf(s3f, dv, bb.w), 0.f);
        *(uint2*)&a1[(size_t)wid * 64 + c * 2] = make_uint2(pk_bf16(o0, o1), pk_bf16(o2, o3));
    }
}

// ---------------------------------------------------------------------------
// GEMM2: h2s[100000,8] = (a1(bf16) @ W2) * dinv[node]
// ---------------------------------------------------------------------------
__global__ __launch_bounds__(256) void k_gemm2(const uint32_t* __restrict__ a1,
                                               const float* __restrict__ W2,
                                               const float* __restrict__ dinv,
                                               float* __restrict__ h2s, int N) {
    __shared__ float w[HID * OUT_F];
    int t = threadIdx.x;
    for (int i = t; i < HID * OUT_F; i += 256) w[i] = W2[i];
    __syncthreads();
    int node = blockIdx.x * 32 + (t >> 3);
    int f = t & 7;
    if (node >= N) return;
    const uint32_t* ar = a1 + (size_t)node * 64;
    float acc = 0.f;
    #pragma unroll 8
    for (int k = 0; k < 64; k++) {
        uint32_t u = ar[k];
        acc = fmaf(bl(u), w[(2 * k) * OUT_F + f], acc);
        acc = fmaf(bh(u), w[(2 * k + 1) * OUT_F + f], acc);
    }
    h2s[(size_t)node * OUT_F + f] = acc * dinv[node];
}

// ---------------------------------------------------------------------------
// Aggregation layer 2 + bias + log_softmax, fused.
// ---------------------------------------------------------------------------
__global__ __launch_bounds__(256) void k_agg2(const float* __restrict__ h2s,
                                              const int* __restrict__ offs,
                                              const int* __restrict__ cnt,
                                              const float* __restrict__ dinv,
                                              const int* __restrict__ ssrc,
                                              const float* __restrict__ b2,
                                              float* __restrict__ out, int N) {
    int wid = (blockIdx.x * 256 + threadIdx.x) >> 6;
    int lane = threadIdx.x & 63;
    if (wid >= N) return;
    int f = lane & 7, g = lane >> 3;
    float dv = dinv[wid];
    int beg = offs[wid], n = cnt[wid];
    float acc = 0.f;
    for (int j = g; j < n; j += 8) {
        int s = ssrc[beg + j];
        acc += h2s[(size_t)s * OUT_F + f];
    }
    acc += __shfl_xor(acc, 8);
    acc += __shfl_xor(acc, 16);
    acc += __shfl_xor(acc, 32);
    acc += h2s[(size_t)wid * OUT_F + f];
    acc = fmaf(acc, dv, b2[f]);
    float m = acc;
    m = fmaxf(m, __shfl_xor(m, 1));
    m = fmaxf(m, __shfl_xor(m, 2));
    m = fmaxf(m, __shfl_xor(m, 4));
    float e = expf(acc - m);
    float ssum = e;
    ssum += __shfl_xor(ssum, 1);
    ssum += __shfl_xor(ssum, 2);
    ssum += __shfl_xor(ssum, 4);
    float res = acc - m - logf(ssum);
    if (lane < 8) out[(size_t)wid * OUT_F + lane] = res;
}

// ---------------------------------------------------------------------------
extern "C" void kernel_launch(void* const* d_in, const int* in_sizes, int n_in,
                              void* d_out, int out_size, void* d_ws, size_t ws_size,
                              hipStream_t stream) {
    const float* x   = (const float*)d_in[0];
    const int*   ei  = (const int*)d_in[1];     // [2, E] flat: src then dst
    const float* W1  = (const float*)d_in[2];
    const float* b1  = (const float*)d_in[3];
    const float* W2  = (const float*)d_in[4];
    const float* b2  = (const float*)d_in[5];
    float* out = (float*)d_out;

    const int N = N_NODES, E = N_EDGES;
    const int* src = ei;
    const int* dst = ei + E;

    char* p = (char*)d_ws;
    auto carve = [&](size_t bytes) -> void* {
        void* r = (void*)p;
        p += (bytes + 511) & ~(size_t)511;
        return r;
    };
    int*      gcnt  = (int*)carve((size_t)NB * 64 * 4);
    int*      gcur  = (int*)carve((size_t)NB * 64 * 4);
    int*      bbase = (int*)carve((size_t)(NB + 1) * 4);
    uint32_t* epk   = (uint32_t*)carve((size_t)E * 4);
    int*      offs  = (int*)carve((size_t)N * 4);
    int*      cnt   = (int*)carve((size_t)N * 4);
    float*    dinv  = (float*)carve((size_t)N * 4);
    int*      ssrc  = (int*)carve((size_t)E * 4);
    ushort*   wbf   = (ushort*)carve((size_t)HID * IN_F * 2);
    uint32_t* hs8   = (uint32_t*)carve((size_t)N * 32 * 4);   // fp8 rows, 128B
    uint32_t* a1    = (uint32_t*)carve((size_t)N * 64 * 4);   // bf16 rows, 256B
    float*    h2s   = (float*)carve((size_t)N * OUT_F * 4);

    hipMemsetAsync(gcnt, 0, (size_t)NB * 64 * 4, stream);

    k_wcast<<<8, 256, 0, stream>>>(W1, wbf);
    k_bhist<<<512, 256, 0, stream>>>(dst, gcnt, E);
    k_bscan<<<1, 512, 0, stream>>>(gcnt, bbase, gcur);
    k_part<<<(E + PASS - 1) / PASS, 256, 0, stream>>>(src, dst, gcur, epk, E);
    k_csr<<<NB, 256, 0, stream>>>(epk, bbase, offs, cnt, dinv, ssrc, N);

    k_gemm1<<<(N + 63) / 64, 256, 0, stream>>>(x, wbf, dinv, hs8, N);
    k_agg1<<<(N * 64 + 255) / 256, 256, 0, stream>>>(hs8, offs, cnt, dinv, ssrc, b1, a1, N);
    k_gemm2<<<(N + 31) / 32, 256, 0, stream>>>(a1, W2, dinv, h2s, N);
    k_agg2<<<(N * 64 + 255) / 256, 256, 0, stream>>>(h2s, offs, cnt, dinv, ssrc, b2, out, N);
}

// Round 5
// 406.257 us; speedup vs baseline: 2.5111x; 1.0756x over previous
//
#include <hip/hip_runtime.h>
#include <hip/hip_bf16.h>
#include <stdint.h>

#define N_NODES 100000
#define N_EDGES 3200000
#define IN_F 256
#define HID 128
#define OUT_F 8

#define NB   391        // node buckets of 256
#define PASS 6144       // edges staged per k_part block (33KB LDS -> 4 blk/CU)
#define CAP  10240      // k_csr LDS stage capacity

typedef short short8 __attribute__((ext_vector_type(8)));
typedef float f32x4 __attribute__((ext_vector_type(4)));
typedef float f32x2 __attribute__((ext_vector_type(2)));

// bf16 pack/unpack helpers (RNE)
__device__ __forceinline__ uint32_t pk_bf16(float a, float b) {
    uint32_t ua = __float_as_uint(a);
    uint32_t ub = __float_as_uint(b);
    ua = (ua + 0x7fff + ((ua >> 16) & 1)) >> 16;
    ub = (ub + 0x7fff + ((ub >> 16) & 1)) & 0xffff0000u;
    return ua | ub;
}
__device__ __forceinline__ float bl(uint32_t u) { return __uint_as_float(u << 16); }
__device__ __forceinline__ float bh(uint32_t u) { return __uint_as_float(u & 0xffff0000u); }

// fp8 e4m3 decode: 4 fp8 in a uint -> 4 floats (HW converter)
__device__ __forceinline__ void dec4(uint32_t u, float& a, float& b, float& c, float& d) {
    f32x2 lo = __builtin_amdgcn_cvt_pk_f32_fp8(u, false);
    f32x2 hi = __builtin_amdgcn_cvt_pk_f32_fp8(u, true);
    a = lo[0]; b = lo[1]; c = hi[0]; d = hi[1];
}

// ---------------------------------------------------------------------------
// Bucket histogram (LDS-aggregated, int4 edge reads)
// ---------------------------------------------------------------------------
__global__ __launch_bounds__(256) void k_bhist(const int* __restrict__ dst,
                                               int* __restrict__ gcnt, int E) {
    __shared__ int lb[NB];
    for (int i = threadIdx.x; i < NB; i += 256) lb[i] = 0;
    __syncthreads();
    int stride = gridDim.x * 256;
    const int4* d4 = (const int4*)dst;
    for (int e = blockIdx.x * 256 + threadIdx.x; e < E / 4; e += stride) {
        int4 d = d4[e];
        atomicAdd(&lb[d.x >> 8], 1);
        atomicAdd(&lb[d.y >> 8], 1);
        atomicAdd(&lb[d.z >> 8], 1);
        atomicAdd(&lb[d.w >> 8], 1);
    }
    __syncthreads();
    for (int i = threadIdx.x; i < NB; i += 256) {
        int c = lb[i];
        if (c) atomicAdd(&gcnt[i * 64], c);
    }
}

__global__ __launch_bounds__(512) void k_bscan(const int* __restrict__ gcnt,
                                               int* __restrict__ bbase,
                                               int* __restrict__ gcur) {
    __shared__ int sc[512];
    int tid = threadIdx.x;
    int v = (tid < NB) ? gcnt[tid * 64] : 0;
    sc[tid] = v;
    __syncthreads();
    for (int d = 1; d < 512; d <<= 1) {
        int t = (tid >= d) ? sc[tid - d] : 0;
        __syncthreads();
        sc[tid] += t;
        __syncthreads();
    }
    int excl = sc[tid] - v;
    if (tid <= NB) bbase[tid] = excl;
    if (tid < NB) gcur[tid * 64] = excl;
}

// ---------------------------------------------------------------------------
// Partition edges into bucket-contiguous regions (LDS-staged flush)
// ---------------------------------------------------------------------------
__global__ __launch_bounds__(256) void k_part(const int* __restrict__ src,
                                              const int* __restrict__ dst,
                                              int* __restrict__ gcur,
                                              uint32_t* __restrict__ epk, int E) {
    __shared__ int lcnt[NB], loff[NB], ladj[NB], lcur[NB];
    __shared__ int sc[512];
    __shared__ uint32_t stage[PASS];
    int tid = threadIdx.x;
    int e0 = blockIdx.x * PASS;

    for (int i = tid; i < NB; i += 256) { lcnt[i] = 0; lcur[i] = 0; }
    __syncthreads();
    for (int i = tid; i < PASS; i += 256) {
        int e = e0 + i;
        if (e < E) atomicAdd(&lcnt[dst[e] >> 8], 1);
    }
    __syncthreads();
    int v0 = (tid < NB) ? lcnt[tid] : 0;
    int v1 = (256 + tid < NB) ? lcnt[256 + tid] : 0;
    sc[tid] = v0; sc[256 + tid] = v1;
    __syncthreads();
    for (int d = 1; d < 512; d <<= 1) {
        int t0 = (tid >= d) ? sc[tid - d] : 0;
        int t1 = (256 + tid >= d) ? sc[256 + tid - d] : 0;
        __syncthreads();
        sc[tid] += t0; sc[256 + tid] += t1;
        __syncthreads();
    }
    if (tid < NB) loff[tid] = sc[tid] - v0;
    if (256 + tid < NB) loff[256 + tid] = sc[256 + tid] - v1;
    __syncthreads();
    for (int b = tid; b < NB; b += 256) {
        int len = lcnt[b];
        if (len > 0) ladj[b] = atomicAdd(&gcur[b * 64], len);
    }
    __syncthreads();
    for (int i = tid; i < PASS; i += 256) {
        int e = e0 + i;
        if (e < E) {
            int d = dst[e];
            int b = d >> 8;
            int r = atomicAdd(&lcur[b], 1);
            stage[loff[b] + r] = (uint32_t)src[e] | ((uint32_t)(d & 255) << 17);
        }
    }
    __syncthreads();
    int wv = tid >> 6, ln = tid & 63;
    for (int b = wv; b < NB; b += 4) {
        int len = lcnt[b], lo = loff[b], gb = ladj[b];
        for (int j = ln; j < len; j += 64) epk[gb + j] = stage[lo + j];
    }
}

// ---------------------------------------------------------------------------
// Per-bucket CSR finalize: offs/cnt/dinv + node-sorted ssrc. 512 threads:
// 8 waves hide LDS-atomic + global latency (391 blocks -> ~1.5/CU).
// ---------------------------------------------------------------------------
__global__ __launch_bounds__(512) void k_csr(const uint32_t* __restrict__ epk,
                                             const int* __restrict__ bbase,
                                             int* __restrict__ offs,
                                             int* __restrict__ cnt,
                                             float* __restrict__ dinv,
                                             int* __restrict__ ssrc, int N) {
    __shared__ int lcnt[256], lcur[256], loff[256];
    __shared__ uint32_t stage[CAP];
    int tid = threadIdx.x, b = blockIdx.x;
    int base = bbase[b], m = bbase[b + 1] - base;

    if (tid < 256) lcnt[tid] = 0;
    __syncthreads();
    for (int i = tid; i < m; i += 512)
        atomicAdd(&lcnt[(epk[base + i] >> 17) & 255], 1);
    __syncthreads();
    int v = (tid < 256) ? lcnt[tid] : 0;
    if (tid < 256) loff[tid] = v;
    __syncthreads();
    for (int d = 1; d < 256; d <<= 1) {
        int t = (tid >= d && tid < 256) ? loff[tid - d] : 0;
        __syncthreads();
        if (tid < 256) loff[tid] += t;
        __syncthreads();
    }
    int excl = (tid < 256) ? (loff[tid] - v) : 0;
    __syncthreads();
    if (tid < 256) {
        loff[tid] = excl;
        lcur[tid] = 0;
        int node = b * 256 + tid;
        if (node < N) {
            offs[node] = base + excl;
            cnt[node] = v;
            dinv[node] = rsqrtf((float)(v + 1));
        }
    }
    __syncthreads();
    if (m <= CAP) {
        for (int i = tid; i < m; i += 512) {
            uint32_t u = epk[base + i];
            int ld = (u >> 17) & 255;
            int r = atomicAdd(&lcur[ld], 1);
            stage[loff[ld] + r] = u & 0x1FFFF;
        }
        __syncthreads();
        for (int i = tid; i < m; i += 512) ssrc[base + i] = (int)stage[i];
    } else {
        for (int i = tid; i < m; i += 512) {
            uint32_t u = epk[base + i];
            int ld = (u >> 17) & 255;
            int r = atomicAdd(&lcur[ld], 1);
            ssrc[base + loff[ld] + r] = (int)(u & 0x1FFFF);
        }
    }
}

// ---------------------------------------------------------------------------
// W1 [256][128] fp32 -> W1bf [128][256] bf16 (transposed, n-major)
// ---------------------------------------------------------------------------
__global__ __launch_bounds__(256) void k_wcast(const float* __restrict__ W1,
                                               ushort* __restrict__ Wbf) {
    __shared__ ushort T[128][33];
    int t = threadIdx.x;
    int k0 = blockIdx.x * 32;
    for (int idx = t; idx < 32 * 128; idx += 256) {
        int k = idx >> 7, n = idx & 127;
        uint32_t uv = __float_as_uint(W1[(size_t)(k0 + k) * HID + n]);
        uv = (uv + 0x7fff + ((uv >> 16) & 1)) >> 16;
        T[n][k] = (ushort)uv;
    }
    __syncthreads();
    for (int idx = t; idx < 32 * 128; idx += 256) {
        int n = idx >> 5, k = idx & 31;
        Wbf[(size_t)n * IN_F + k0 + k] = T[n][k];
    }
}

// ---------------------------------------------------------------------------
// GEMM1 (MFMA bf16): Hs8[100000][128](fp8 e4m3) = (X @ W1) * dinv[row]
// ---------------------------------------------------------------------------
__global__ __launch_bounds__(256) void k_gemm1(const float* __restrict__ X,
                                               const ushort* __restrict__ Wbf,
                                               const float* __restrict__ dinv,
                                               uint32_t* __restrict__ Hs8, int M) {
    __shared__ uint32_t As[64 * 20];    // 64 rows x 40 bf16
    __shared__ uint32_t Bs[128 * 20];   // 128 n-rows x 40 bf16
    __shared__ float st[4][16 * 132];   // per-wave epilogue stage
    int t = threadIdx.x;
    int lane = t & 63, w = t >> 6;
    int q = lane >> 4, c16 = lane & 15;
    int row0 = blockIdx.x * 64;

    int ar = t >> 2, a4 = (t & 3);
    int grow = row0 + ar; if (grow >= M) grow = M - 1;
    const float* xrow = X + (size_t)grow * IN_F;
    int bn = t >> 1, b1h = (t & 1);
    const ushort* wrow = Wbf + (size_t)bn * IN_F;

    f32x4 acc[8];
    #pragma unroll
    for (int j = 0; j < 8; j++) acc[j] = (f32x4){0.f, 0.f, 0.f, 0.f};

    for (int kc = 0; kc < IN_F; kc += 32) {
        float4 x0 = *(const float4*)(xrow + kc + a4 * 8);
        float4 x1 = *(const float4*)(xrow + kc + a4 * 8 + 4);
        uint4 wv0 = *(const uint4*)(wrow + kc + b1h * 16);
        uint4 wv1 = *(const uint4*)(wrow + kc + b1h * 16 + 8);
        __syncthreads();
        *(uint2*)&As[ar * 20 + a4 * 4]     = make_uint2(pk_bf16(x0.x, x0.y), pk_bf16(x0.z, x0.w));
        *(uint2*)&As[ar * 20 + a4 * 4 + 2] = make_uint2(pk_bf16(x1.x, x1.y), pk_bf16(x1.z, x1.w));
        *(uint4*)&Bs[bn * 20 + b1h * 8]     = wv0;
        *(uint4*)&Bs[bn * 20 + b1h * 8 + 4] = wv1;
        __syncthreads();
        short8 af = *(const short8*)&As[(w * 16 + c16) * 20 + q * 4];
        #pragma unroll
        for (int j = 0; j < 8; j++) {
            short8 bf = *(const short8*)&Bs[(j * 16 + c16) * 20 + q * 4];
            acc[j] = __builtin_amdgcn_mfma_f32_16x16x32_bf16(af, bf, acc[j], 0, 0, 0);
        }
    }
    float dv[4];
    #pragma unroll
    for (int r = 0; r < 4; r++) {
        int gr = row0 + w * 16 + q * 4 + r;
        dv[r] = (gr < M) ? dinv[gr] : 0.f;
    }
    #pragma unroll
    for (int j = 0; j < 8; j++)
        #pragma unroll
        for (int r = 0; r < 4; r++)
            st[w][(q * 4 + r) * 132 + j * 16 + c16] = acc[j][r] * dv[r];
    __syncthreads();
    #pragma unroll
    for (int p = 0; p < 4; p++) {
        int rr = p * 4 + q;
        int gr = row0 + w * 16 + rr;
        float4 v0 = *(const float4*)&st[w][rr * 132 + c16 * 8];
        float4 v1 = *(const float4*)&st[w][rr * 132 + c16 * 8 + 4];
        uint32_t lo = 0, hi = 0;
        lo = __builtin_amdgcn_cvt_pk_fp8_f32(v0.x, v0.y, lo, false);
        lo = __builtin_amdgcn_cvt_pk_fp8_f32(v0.z, v0.w, lo, true);
        hi = __builtin_amdgcn_cvt_pk_fp8_f32(v1.x, v1.y, hi, false);
        hi = __builtin_amdgcn_cvt_pk_fp8_f32(v1.z, v1.w, hi, true);
        if (gr < M) *(uint2*)&Hs8[(size_t)gr * 32 + c16 * 2] = make_uint2(lo, hi);
    }
}

// ---------------------------------------------------------------------------
// Aggregation layer 1: wave per node, fp8 rows (128B). Half-wave per edge,
// 8 loads in flight per half-wave (16 edges per wave iteration).
// ---------------------------------------------------------------------------
__global__ __launch_bounds__(256) void k_agg1(const uint32_t* __restrict__ hs,
                                              const int* __restrict__ offs,
                                              const int* __restrict__ cnt,
                                              const float* __restrict__ dinv,
                                              const int* __restrict__ ssrc,
                                              const float* __restrict__ b1,
                                              uint32_t* __restrict__ a1, int N) {
    int wid = (blockIdx.x * 256 + threadIdx.x) >> 6;
    int lane = threadIdx.x & 63;
    if (wid >= N) return;
    int h = lane >> 5, c = lane & 31;
    float dv = dinv[wid];
    float s0f = 0.f, s1f = 0.f, s2f = 0.f, s3f = 0.f;
    if (h == 0) {
        dec4(hs[(size_t)wid * 32 + c], s0f, s1f, s2f, s3f);
    }
    int beg = offs[wid], n = cnt[wid];
    const int* sp = ssrc + beg;
    int j = h;
    float x0, x1, x2, x3;
    for (; j + 14 < n; j += 16) {
        int e0 = sp[j],      e1 = sp[j + 2],  e2 = sp[j + 4],  e3 = sp[j + 6];
        int e4 = sp[j + 8],  e5 = sp[j + 10], e6 = sp[j + 12], e7 = sp[j + 14];
        uint32_t u0 = hs[(size_t)e0 * 32 + c];
        uint32_t u1 = hs[(size_t)e1 * 32 + c];
        uint32_t u2 = hs[(size_t)e2 * 32 + c];
        uint32_t u3 = hs[(size_t)e3 * 32 + c];
        uint32_t u4 = hs[(size_t)e4 * 32 + c];
        uint32_t u5 = hs[(size_t)e5 * 32 + c];
        uint32_t u6 = hs[(size_t)e6 * 32 + c];
        uint32_t u7 = hs[(size_t)e7 * 32 + c];
        dec4(u0, x0, x1, x2, x3); s0f += x0; s1f += x1; s2f += x2; s3f += x3;
        dec4(u1, x0, x1, x2, x3); s0f += x0; s1f += x1; s2f += x2; s3f += x3;
        dec4(u2, x0, x1, x2, x3); s0f += x0; s1f += x1; s2f += x2; s3f += x3;
        dec4(u3, x0, x1, x2, x3); s0f += x0; s1f += x1; s2f += x2; s3f += x3;
        dec4(u4, x0, x1, x2, x3); s0f += x0; s1f += x1; s2f += x2; s3f += x3;
        dec4(u5, x0, x1, x2, x3); s0f += x0; s1f += x1; s2f += x2; s3f += x3;
        dec4(u6, x0, x1, x2, x3); s0f += x0; s1f += x1; s2f += x2; s3f += x3;
        dec4(u7, x0, x1, x2, x3); s0f += x0; s1f += x1; s2f += x2; s3f += x3;
    }
    for (; j + 6 < n; j += 8) {
        int e0 = sp[j], e1 = sp[j + 2], e2 = sp[j + 4], e3 = sp[j + 6];
        uint32_t u0 = hs[(size_t)e0 * 32 + c];
        uint32_t u1 = hs[(size_t)e1 * 32 + c];
        uint32_t u2 = hs[(size_t)e2 * 32 + c];
        uint32_t u3 = hs[(size_t)e3 * 32 + c];
        dec4(u0, x0, x1, x2, x3); s0f += x0; s1f += x1; s2f += x2; s3f += x3;
        dec4(u1, x0, x1, x2, x3); s0f += x0; s1f += x1; s2f += x2; s3f += x3;
        dec4(u2, x0, x1, x2, x3); s0f += x0; s1f += x1; s2f += x2; s3f += x3;
        dec4(u3, x0, x1, x2, x3); s0f += x0; s1f += x1; s2f += x2; s3f += x3;
    }
    for (; j < n; j += 2) {
        uint32_t u = hs[(size_t)sp[j] * 32 + c];
        dec4(u, x0, x1, x2, x3); s0f += x0; s1f += x1; s2f += x2; s3f += x3;
    }
    s0f += __shfl_xor(s0f, 32);
    s1f += __shfl_xor(s1f, 32);
    s2f += __shfl_xor(s2f, 32);
    s3f += __shfl_xor(s3f, 32);
    if (h == 0) {
        float4 bb = *(const float4*)(b1 + c * 4);
        float o0 = fmaxf(fmaf(s0f, dv, bb.x), 0.f);
        float o1 = fmaxf(fmaf(s1f, dv, bb.y), 0.f);
        float o2 = fmaxf(fmaf(s2f, dv, bb.z), 0.f);
        float o3 = fmaxf(fmaf(s3f, dv, bb.w), 0.f);
        *(uint2*)&a1[(size_t)wid * 64 + c * 2] = make_uint2(pk_bf16(o0, o1), pk_bf16(o2, o3));
    }
}

// ---------------------------------------------------------------------------
// GEMM2: h2s[100000,8] = (a1(bf16) @ W2) * dinv[node]
// ---------------------------------------------------------------------------
__global__ __launch_bounds__(256) void k_gemm2(const uint32_t* __restrict__ a1,
                                               const float* __restrict__ W2,
                                               const float* __restrict__ dinv,
                                               float* __restrict__ h2s, int N) {
    __shared__ float w[HID * OUT_F];
    int t = threadIdx.x;
    for (int i = t; i < HID * OUT_F; i += 256) w[i] = W2[i];
    __syncthreads();
    int node = blockIdx.x * 32 + (t >> 3);
    int f = t & 7;
    if (node >= N) return;
    const uint32_t* ar = a1 + (size_t)node * 64;
    float acc = 0.f;
    #pragma unroll 8
    for (int k = 0; k < 64; k++) {
        uint32_t u = ar[k];
        acc = fmaf(bl(u), w[(2 * k) * OUT_F + f], acc);
        acc = fmaf(bh(u), w[(2 * k + 1) * OUT_F + f], acc);
    }
    h2s[(size_t)node * OUT_F + f] = acc * dinv[node];
}

// ---------------------------------------------------------------------------
// Aggregation layer 2 + bias + log_softmax, fused.
// ---------------------------------------------------------------------------
__global__ __launch_bounds__(256) void k_agg2(const float* __restrict__ h2s,
                                              const int* __restrict__ offs,
                                              const int* __restrict__ cnt,
                                              const float* __restrict__ dinv,
                                              const int* __restrict__ ssrc,
                                              const float* __restrict__ b2,
                                              float* __restrict__ out, int N) {
    int wid = (blockIdx.x * 256 + threadIdx.x) >> 6;
    int lane = threadIdx.x & 63;
    if (wid >= N) return;
    int f = lane & 7, g = lane >> 3;
    float dv = dinv[wid];
    int beg = offs[wid], n = cnt[wid];
    float acc = 0.f;
    for (int j = g; j < n; j += 8) {
        int s = ssrc[beg + j];
        acc += h2s[(size_t)s * OUT_F + f];
    }
    acc += __shfl_xor(acc, 8);
    acc += __shfl_xor(acc, 16);
    acc += __shfl_xor(acc, 32);
    acc += h2s[(size_t)wid * OUT_F + f];
    acc = fmaf(acc, dv, b2[f]);
    float m = acc;
    m = fmaxf(m, __shfl_xor(m, 1));
    m = fmaxf(m, __shfl_xor(m, 2));
    m = fmaxf(m, __shfl_xor(m, 4));
    float e = expf(acc - m);
    float ssum = e;
    ssum += __shfl_xor(ssum, 1);
    ssum += __shfl_xor(ssum, 2);
    ssum += __shfl_xor(ssum, 4);
    float res = acc - m - logf(ssum);
    if (lane < 8) out[(size_t)wid * OUT_F + lane] = res;
}

// ---------------------------------------------------------------------------
extern "C" void kernel_launch(void* const* d_in, const int* in_sizes, int n_in,
                              void* d_out, int out_size, void* d_ws, size_t ws_size,
                              hipStream_t stream) {
    const float* x   = (const float*)d_in[0];
    const int*   ei  = (const int*)d_in[1];     // [2, E] flat: src then dst
    const float* W1  = (const float*)d_in[2];
    const float* b1  = (const float*)d_in[3];
    const float* W2  = (const float*)d_in[4];
    const float* b2  = (const float*)d_in[5];
    float* out = (float*)d_out;

    const int N = N_NODES, E = N_EDGES;
    const int* src = ei;
    const int* dst = ei + E;

    char* p = (char*)d_ws;
    auto carve = [&](size_t bytes) -> void* {
        void* r = (void*)p;
        p += (bytes + 511) & ~(size_t)511;
        return r;
    };
    int*      gcnt  = (int*)carve((size_t)NB * 64 * 4);
    int*      gcur  = (int*)carve((size_t)NB * 64 * 4);
    int*      bbase = (int*)carve((size_t)(NB + 1) * 4);
    uint32_t* epk   = (uint32_t*)carve((size_t)E * 4);
    int*      offs  = (int*)carve((size_t)N * 4);
    int*      cnt   = (int*)carve((size_t)N * 4);
    float*    dinv  = (float*)carve((size_t)N * 4);
    int*      ssrc  = (int*)carve((size_t)E * 4);
    ushort*   wbf   = (ushort*)carve((size_t)HID * IN_F * 2);
    uint32_t* hs8   = (uint32_t*)carve((size_t)N * 32 * 4);   // fp8 rows, 128B
    uint32_t* a1    = (uint32_t*)carve((size_t)N * 64 * 4);   // bf16 rows, 256B
    float*    h2s   = (float*)carve((size_t)N * OUT_F * 4);

    hipMemsetAsync(gcnt, 0, (size_t)NB * 64 * 4, stream);

    k_wcast<<<8, 256, 0, stream>>>(W1, wbf);
    k_bhist<<<512, 256, 0, stream>>>(dst, gcnt, E);
    k_bscan<<<1, 512, 0, stream>>>(gcnt, bbase, gcur);
    k_part<<<(E + PASS - 1) / PASS, 256, 0, stream>>>(src, dst, gcur, epk, E);
    k_csr<<<NB, 512, 0, stream>>>(epk, bbase, offs, cnt, dinv, ssrc, N);

    k_gemm1<<<(N + 63) / 64, 256, 0, stream>>>(x, wbf, dinv, hs8, N);
    k_agg1<<<(N * 64 + 255) / 256, 256, 0, stream>>>(hs8, offs, cnt, dinv, ssrc, b1, a1, N);
    k_gemm2<<<(N + 31) / 32, 256, 0, stream>>>(a1, W2, dinv, h2s, N);
    k_agg2<<<(N * 64 + 255) / 256, 256, 0, stream>>>(h2s, offs, cnt, dinv, ssrc, b2, out, N);
}

// Round 6
// 379.166 us; speedup vs baseline: 2.6905x; 1.0715x over previous
//
#include <hip/hip_runtime.h>
#include <hip/hip_bf16.h>
#include <stdint.h>

#define N_NODES 100000
#define N_EDGES 3200000
#define IN_F 256
#define HID 128
#define OUT_F 8

#define NB   391        // node buckets of 256
#define PASS 6144       // edges staged per k_part block (33KB LDS -> 4 blk/CU)
#define CAP  10240      // k_csr LDS stage capacity

typedef short short8 __attribute__((ext_vector_type(8)));
typedef float f32x4 __attribute__((ext_vector_type(4)));
typedef float f32x2 __attribute__((ext_vector_type(2)));

// bf16 pack helpers (RNE)
__device__ __forceinline__ uint32_t pk_bf16(float a, float b) {
    uint32_t ua = __float_as_uint(a);
    uint32_t ub = __float_as_uint(b);
    ua = (ua + 0x7fff + ((ua >> 16) & 1)) >> 16;
    ub = (ub + 0x7fff + ((ub >> 16) & 1)) & 0xffff0000u;
    return ua | ub;
}

// ---------------------------------------------------------------------------
// Bucket histogram (LDS-aggregated, int4 edge reads)
// ---------------------------------------------------------------------------
__global__ __launch_bounds__(256) void k_bhist(const int* __restrict__ dst,
                                               int* __restrict__ gcnt, int E) {
    __shared__ int lb[NB];
    for (int i = threadIdx.x; i < NB; i += 256) lb[i] = 0;
    __syncthreads();
    int stride = gridDim.x * 256;
    const int4* d4 = (const int4*)dst;
    for (int e = blockIdx.x * 256 + threadIdx.x; e < E / 4; e += stride) {
        int4 d = d4[e];
        atomicAdd(&lb[d.x >> 8], 1);
        atomicAdd(&lb[d.y >> 8], 1);
        atomicAdd(&lb[d.z >> 8], 1);
        atomicAdd(&lb[d.w >> 8], 1);
    }
    __syncthreads();
    for (int i = threadIdx.x; i < NB; i += 256) {
        int c = lb[i];
        if (c) atomicAdd(&gcnt[i * 64], c);
    }
}

__global__ __launch_bounds__(512) void k_bscan(const int* __restrict__ gcnt,
                                               int* __restrict__ bbase,
                                               int* __restrict__ gcur) {
    __shared__ int sc[512];
    int tid = threadIdx.x;
    int v = (tid < NB) ? gcnt[tid * 64] : 0;
    sc[tid] = v;
    __syncthreads();
    for (int d = 1; d < 512; d <<= 1) {
        int t = (tid >= d) ? sc[tid - d] : 0;
        __syncthreads();
        sc[tid] += t;
        __syncthreads();
    }
    int excl = sc[tid] - v;
    if (tid <= NB) bbase[tid] = excl;
    if (tid < NB) gcur[tid * 64] = excl;
}

// ---------------------------------------------------------------------------
// Partition edges into bucket-contiguous regions (LDS-staged flush), 512 thr
// ---------------------------------------------------------------------------
__global__ __launch_bounds__(512) void k_part(const int* __restrict__ src,
                                              const int* __restrict__ dst,
                                              int* __restrict__ gcur,
                                              uint32_t* __restrict__ epk, int E) {
    __shared__ int lcnt[NB], loff[NB], ladj[NB], lcur[NB];
    __shared__ int sc[512];
    __shared__ uint32_t stage[PASS];
    int tid = threadIdx.x;
    int e0 = blockIdx.x * PASS;

    for (int i = tid; i < NB; i += 512) { lcnt[i] = 0; lcur[i] = 0; }
    __syncthreads();
    for (int i = tid; i < PASS; i += 512) {
        int e = e0 + i;
        if (e < E) atomicAdd(&lcnt[dst[e] >> 8], 1);
    }
    __syncthreads();
    int v = (tid < NB) ? lcnt[tid] : 0;
    sc[tid] = v;
    __syncthreads();
    for (int d = 1; d < 512; d <<= 1) {
        int t = (tid >= d) ? sc[tid - d] : 0;
        __syncthreads();
        sc[tid] += t;
        __syncthreads();
    }
    if (tid < NB) loff[tid] = sc[tid] - v;
    __syncthreads();
    if (tid < NB) {
        int len = lcnt[tid];
        if (len > 0) ladj[tid] = atomicAdd(&gcur[tid * 64], len);
    }
    __syncthreads();
    for (int i = tid; i < PASS; i += 512) {
        int e = e0 + i;
        if (e < E) {
            int d = dst[e];
            int b = d >> 8;
            int r = atomicAdd(&lcur[b], 1);
            stage[loff[b] + r] = (uint32_t)src[e] | ((uint32_t)(d & 255) << 17);
        }
    }
    __syncthreads();
    int wv = tid >> 6, ln = tid & 63;
    for (int b = wv; b < NB; b += 8) {
        int len = lcnt[b], lo = loff[b], gb = ladj[b];
        for (int j = ln; j < len; j += 64) epk[gb + j] = stage[lo + j];
    }
}

// ---------------------------------------------------------------------------
// Per-bucket CSR finalize: offs/cnt/dinv + node-sorted ssrc. 1024 threads.
// ---------------------------------------------------------------------------
__global__ __launch_bounds__(1024) void k_csr(const uint32_t* __restrict__ epk,
                                              const int* __restrict__ bbase,
                                              int* __restrict__ offs,
                                              int* __restrict__ cnt,
                                              float* __restrict__ dinv,
                                              int* __restrict__ ssrc, int N) {
    __shared__ int lcnt[256], lcur[256], loff[256];
    __shared__ uint32_t stage[CAP];
    int tid = threadIdx.x, b = blockIdx.x;
    int base = bbase[b], m = bbase[b + 1] - base;

    if (tid < 256) lcnt[tid] = 0;
    __syncthreads();
    for (int i = tid; i < m; i += 1024)
        atomicAdd(&lcnt[(epk[base + i] >> 17) & 255], 1);
    __syncthreads();
    int v = (tid < 256) ? lcnt[tid] : 0;
    if (tid < 256) loff[tid] = v;
    __syncthreads();
    for (int d = 1; d < 256; d <<= 1) {
        int t = (tid >= d && tid < 256) ? loff[tid - d] : 0;
        __syncthreads();
        if (tid < 256) loff[tid] += t;
        __syncthreads();
    }
    int excl = (tid < 256) ? (loff[tid] - v) : 0;
    __syncthreads();
    if (tid < 256) {
        loff[tid] = excl;
        lcur[tid] = 0;
        int node = b * 256 + tid;
        if (node < N) {
            offs[node] = base + excl;
            cnt[node] = v;
            dinv[node] = rsqrtf((float)(v + 1));
        }
    }
    __syncthreads();
    if (m <= CAP) {
        for (int i = tid; i < m; i += 1024) {
            uint32_t u = epk[base + i];
            int ld = (u >> 17) & 255;
            int r = atomicAdd(&lcur[ld], 1);
            stage[loff[ld] + r] = u & 0x1FFFF;
        }
        __syncthreads();
        for (int i = tid; i < m; i += 1024) ssrc[base + i] = (int)stage[i];
    } else {
        for (int i = tid; i < m; i += 1024) {
            uint32_t u = epk[base + i];
            int ld = (u >> 17) & 255;
            int r = atomicAdd(&lcur[ld], 1);
            ssrc[base + loff[ld] + r] = (int)(u & 0x1FFFF);
        }
    }
}

// ---------------------------------------------------------------------------
// W1 [256][128] fp32 -> W1bf [128][256] bf16 (transposed, n-major)
// ---------------------------------------------------------------------------
__global__ __launch_bounds__(256) void k_wcast(const float* __restrict__ W1,
                                               ushort* __restrict__ Wbf) {
    __shared__ ushort T[128][33];
    int t = threadIdx.x;
    int k0 = blockIdx.x * 32;
    for (int idx = t; idx < 32 * 128; idx += 256) {
        int k = idx >> 7, n = idx & 127;
        uint32_t uv = __float_as_uint(W1[(size_t)(k0 + k) * HID + n]);
        uv = (uv + 0x7fff + ((uv >> 16) & 1)) >> 16;
        T[n][k] = (ushort)uv;
    }
    __syncthreads();
    for (int idx = t; idx < 32 * 128; idx += 256) {
        int n = idx >> 5, k = idx & 31;
        Wbf[(size_t)n * IN_F + k0 + k] = T[n][k];
    }
}

// ---------------------------------------------------------------------------
// GEMM1 (MFMA bf16): Hs8[100000][128](fp8 e4m3) = (X @ W1) * dinv[row]
// ---------------------------------------------------------------------------
__global__ __launch_bounds__(256) void k_gemm1(const float* __restrict__ X,
                                               const ushort* __restrict__ Wbf,
                                               const float* __restrict__ dinv,
                                               uint32_t* __restrict__ Hs8, int M) {
    __shared__ uint32_t As[64 * 20];    // 64 rows x 40 bf16
    __shared__ uint32_t Bs[128 * 20];   // 128 n-rows x 40 bf16
    __shared__ float st[4][16 * 132];   // per-wave epilogue stage
    int t = threadIdx.x;
    int lane = t & 63, w = t >> 6;
    int q = lane >> 4, c16 = lane & 15;
    int row0 = blockIdx.x * 64;

    int ar = t >> 2, a4 = (t & 3);
    int grow = row0 + ar; if (grow >= M) grow = M - 1;
    const float* xrow = X + (size_t)grow * IN_F;
    int bn = t >> 1, b1h = (t & 1);
    const ushort* wrow = Wbf + (size_t)bn * IN_F;

    f32x4 acc[8];
    #pragma unroll
    for (int j = 0; j < 8; j++) acc[j] = (f32x4){0.f, 0.f, 0.f, 0.f};

    for (int kc = 0; kc < IN_F; kc += 32) {
        float4 x0 = *(const float4*)(xrow + kc + a4 * 8);
        float4 x1 = *(const float4*)(xrow + kc + a4 * 8 + 4);
        uint4 wv0 = *(const uint4*)(wrow + kc + b1h * 16);
        uint4 wv1 = *(const uint4*)(wrow + kc + b1h * 16 + 8);
        __syncthreads();
        *(uint2*)&As[ar * 20 + a4 * 4]     = make_uint2(pk_bf16(x0.x, x0.y), pk_bf16(x0.z, x0.w));
        *(uint2*)&As[ar * 20 + a4 * 4 + 2] = make_uint2(pk_bf16(x1.x, x1.y), pk_bf16(x1.z, x1.w));
        *(uint4*)&Bs[bn * 20 + b1h * 8]     = wv0;
        *(uint4*)&Bs[bn * 20 + b1h * 8 + 4] = wv1;
        __syncthreads();
        short8 af = *(const short8*)&As[(w * 16 + c16) * 20 + q * 4];
        #pragma unroll
        for (int j = 0; j < 8; j++) {
            short8 bf = *(const short8*)&Bs[(j * 16 + c16) * 20 + q * 4];
            acc[j] = __builtin_amdgcn_mfma_f32_16x16x32_bf16(af, bf, acc[j], 0, 0, 0);
        }
    }
    float dv[4];
    #pragma unroll
    for (int r = 0; r < 4; r++) {
        int gr = row0 + w * 16 + q * 4 + r;
        dv[r] = (gr < M) ? dinv[gr] : 0.f;
    }
    #pragma unroll
    for (int j = 0; j < 8; j++)
        #pragma unroll
        for (int r = 0; r < 4; r++)
            st[w][(q * 4 + r) * 132 + j * 16 + c16] = acc[j][r] * dv[r];
    __syncthreads();
    #pragma unroll
    for (int p = 0; p < 4; p++) {
        int rr = p * 4 + q;
        int gr = row0 + w * 16 + rr;
        float4 v0 = *(const float4*)&st[w][rr * 132 + c16 * 8];
        float4 v1 = *(const float4*)&st[w][rr * 132 + c16 * 8 + 4];
        uint32_t lo = 0, hi = 0;
        lo = __builtin_amdgcn_cvt_pk_fp8_f32(v0.x, v0.y, lo, false);
        lo = __builtin_amdgcn_cvt_pk_fp8_f32(v0.z, v0.w, lo, true);
        hi = __builtin_amdgcn_cvt_pk_fp8_f32(v1.x, v1.y, hi, false);
        hi = __builtin_amdgcn_cvt_pk_fp8_f32(v1.z, v1.w, hi, true);
        if (gr < M) *(uint2*)&Hs8[(size_t)gr * 32 + c16 * 2] = make_uint2(lo, hi);
    }
}

// ---------------------------------------------------------------------------
// Aggregation layer 1 + ReLU + fused GEMM2: wave per node, fp8 rows (128B).
// Half-wave per edge, 8 loads in flight; packed f32x2 accumulate.
// After cross-half combine (both halves hold full sums), half h computes
// output feats [4h,4h+4) via LDS W2^T (float4 reads) + shuffle reduction.
// Writes h2s directly; a1 never materialized.
// ---------------------------------------------------------------------------
__global__ __launch_bounds__(256) void k_agg1(const uint32_t* __restrict__ hs,
                                              const int* __restrict__ offs,
                                              const int* __restrict__ cnt,
                                              const float* __restrict__ dinv,
                                              const int* __restrict__ ssrc,
                                              const float* __restrict__ b1,
                                              const float* __restrict__ W2,
                                              float* __restrict__ h2s, int N) {
    __shared__ float w2t[OUT_F * HID];   // transposed: w2t[f*128+k] = W2[k*8+f]
    int t = threadIdx.x;
    for (int i = t; i < OUT_F * HID; i += 256) {
        int f = i & 7, k = i >> 3;
        w2t[f * HID + k] = W2[k * OUT_F + f];
    }
    __syncthreads();
    int wid = (blockIdx.x * 256 + t) >> 6;
    int lane = t & 63;
    if (wid >= N) return;
    int h = lane >> 5, c = lane & 31;
    float dv = dinv[wid];
    f32x2 s01 = {0.f, 0.f}, s23 = {0.f, 0.f};
    if (h == 0) {
        uint32_t u = hs[(size_t)wid * 32 + c];
        s01 = __builtin_amdgcn_cvt_pk_f32_fp8(u, false);
        s23 = __builtin_amdgcn_cvt_pk_f32_fp8(u, true);
    }
    int beg = offs[wid], n = cnt[wid];
    const int* sp = ssrc + beg;
    int j = h;
    for (; j + 14 < n; j += 16) {
        int e0 = sp[j],      e1 = sp[j + 2],  e2 = sp[j + 4],  e3 = sp[j + 6];
        int e4 = sp[j + 8],  e5 = sp[j + 10], e6 = sp[j + 12], e7 = sp[j + 14];
        uint32_t u0 = hs[(size_t)e0 * 32 + c];
        uint32_t u1 = hs[(size_t)e1 * 32 + c];
        uint32_t u2 = hs[(size_t)e2 * 32 + c];
        uint32_t u3 = hs[(size_t)e3 * 32 + c];
        uint32_t u4 = hs[(size_t)e4 * 32 + c];
        uint32_t u5 = hs[(size_t)e5 * 32 + c];
        uint32_t u6 = hs[(size_t)e6 * 32 + c];
        uint32_t u7 = hs[(size_t)e7 * 32 + c];
        s01 += __builtin_amdgcn_cvt_pk_f32_fp8(u0, false); s23 += __builtin_amdgcn_cvt_pk_f32_fp8(u0, true);
        s01 += __builtin_amdgcn_cvt_pk_f32_fp8(u1, false); s23 += __builtin_amdgcn_cvt_pk_f32_fp8(u1, true);
        s01 += __builtin_amdgcn_cvt_pk_f32_fp8(u2, false); s23 += __builtin_amdgcn_cvt_pk_f32_fp8(u2, true);
        s01 += __builtin_amdgcn_cvt_pk_f32_fp8(u3, false); s23 += __builtin_amdgcn_cvt_pk_f32_fp8(u3, true);
        s01 += __builtin_amdgcn_cvt_pk_f32_fp8(u4, false); s23 += __builtin_amdgcn_cvt_pk_f32_fp8(u4, true);
        s01 += __builtin_amdgcn_cvt_pk_f32_fp8(u5, false); s23 += __builtin_amdgcn_cvt_pk_f32_fp8(u5, true);
        s01 += __builtin_amdgcn_cvt_pk_f32_fp8(u6, false); s23 += __builtin_amdgcn_cvt_pk_f32_fp8(u6, true);
        s01 += __builtin_amdgcn_cvt_pk_f32_fp8(u7, false); s23 += __builtin_amdgcn_cvt_pk_f32_fp8(u7, true);
    }
    for (; j + 6 < n; j += 8) {
        int e0 = sp[j], e1 = sp[j + 2], e2 = sp[j + 4], e3 = sp[j + 6];
        uint32_t u0 = hs[(size_t)e0 * 32 + c];
        uint32_t u1 = hs[(size_t)e1 * 32 + c];
        uint32_t u2 = hs[(size_t)e2 * 32 + c];
        uint32_t u3 = hs[(size_t)e3 * 32 + c];
        s01 += __builtin_amdgcn_cvt_pk_f32_fp8(u0, false); s23 += __builtin_amdgcn_cvt_pk_f32_fp8(u0, true);
        s01 += __builtin_amdgcn_cvt_pk_f32_fp8(u1, false); s23 += __builtin_amdgcn_cvt_pk_f32_fp8(u1, true);
        s01 += __builtin_amdgcn_cvt_pk_f32_fp8(u2, false); s23 += __builtin_amdgcn_cvt_pk_f32_fp8(u2, true);
        s01 += __builtin_amdgcn_cvt_pk_f32_fp8(u3, false); s23 += __builtin_amdgcn_cvt_pk_f32_fp8(u3, true);
    }
    for (; j < n; j += 2) {
        uint32_t u = hs[(size_t)sp[j] * 32 + c];
        s01 += __builtin_amdgcn_cvt_pk_f32_fp8(u, false);
        s23 += __builtin_amdgcn_cvt_pk_f32_fp8(u, true);
    }
    // combine halves (both halves end with identical full sums)
    s01[0] += __shfl_xor(s01[0], 32);
    s01[1] += __shfl_xor(s01[1], 32);
    s23[0] += __shfl_xor(s23[0], 32);
    s23[1] += __shfl_xor(s23[1], 32);
    // bias + ReLU (fp32, no bf16 round-trip)
    float4 bb = *(const float4*)(b1 + c * 4);
    float o0 = fmaxf(fmaf(s01[0], dv, bb.x), 0.f);
    float o1 = fmaxf(fmaf(s01[1], dv, bb.y), 0.f);
    float o2 = fmaxf(fmaf(s23[0], dv, bb.z), 0.f);
    float o3 = fmaxf(fmaf(s23[1], dv, bb.w), 0.f);
    // fused GEMM2 partial: half h computes feats f0..f0+3
    int f0 = h * 4;
    float p[4];
    #pragma unroll
    for (int f = 0; f < 4; f++) {
        float4 wv = *(const float4*)&w2t[(f0 + f) * HID + c * 4];
        p[f] = o0 * wv.x + o1 * wv.y + o2 * wv.z + o3 * wv.w;
    }
    #pragma unroll
    for (int d = 1; d < 32; d <<= 1) {
        #pragma unroll
        for (int f = 0; f < 4; f++) p[f] += __shfl_xor(p[f], d);
    }
    if (c == 0) {
        float4 ov = make_float4(p[0] * dv, p[1] * dv, p[2] * dv, p[3] * dv);
        *(float4*)&h2s[(size_t)wid * OUT_F + f0] = ov;
    }
}

// ---------------------------------------------------------------------------
// Aggregation layer 2 + bias + log_softmax, fused; 4-deep gather MLP.
// ---------------------------------------------------------------------------
__global__ __launch_bounds__(256) void k_agg2(const float* __restrict__ h2s,
                                              const int* __restrict__ offs,
                                              const int* __restrict__ cnt,
                                              const float* __restrict__ dinv,
                                              const int* __restrict__ ssrc,
                                              const float* __restrict__ b2,
                                              float* __restrict__ out, int N) {
    int wid = (blockIdx.x * 256 + threadIdx.x) >> 6;
    int lane = threadIdx.x & 63;
    if (wid >= N) return;
    int f = lane & 7, g = lane >> 3;
    float dv = dinv[wid];
    int beg = offs[wid], n = cnt[wid];
    const int* sp = ssrc + beg;
    float acc = 0.f;
    int j = g;
    for (; j + 24 < n; j += 32) {
        int s0 = sp[j], s1 = sp[j + 8], s2 = sp[j + 16], s3 = sp[j + 24];
        float v0 = h2s[(size_t)s0 * OUT_F + f];
        float v1 = h2s[(size_t)s1 * OUT_F + f];
        float v2 = h2s[(size_t)s2 * OUT_F + f];
        float v3 = h2s[(size_t)s3 * OUT_F + f];
        acc += v0 + v1 + v2 + v3;
    }
    for (; j < n; j += 8) acc += h2s[(size_t)sp[j] * OUT_F + f];
    acc += __shfl_xor(acc, 8);
    acc += __shfl_xor(acc, 16);
    acc += __shfl_xor(acc, 32);
    acc += h2s[(size_t)wid * OUT_F + f];
    acc = fmaf(acc, dv, b2[f]);
    float m = acc;
    m = fmaxf(m, __shfl_xor(m, 1));
    m = fmaxf(m, __shfl_xor(m, 2));
    m = fmaxf(m, __shfl_xor(m, 4));
    float e = expf(acc - m);
    float ssum = e;
    ssum += __shfl_xor(ssum, 1);
    ssum += __shfl_xor(ssum, 2);
    ssum += __shfl_xor(ssum, 4);
    float res = acc - m - logf(ssum);
    if (lane < 8) out[(size_t)wid * OUT_F + lane] = res;
}

// ---------------------------------------------------------------------------
extern "C" void kernel_launch(void* const* d_in, const int* in_sizes, int n_in,
                              void* d_out, int out_size, void* d_ws, size_t ws_size,
                              hipStream_t stream) {
    const float* x   = (const float*)d_in[0];
    const int*   ei  = (const int*)d_in[1];     // [2, E] flat: src then dst
    const float* W1  = (const float*)d_in[2];
    const float* b1  = (const float*)d_in[3];
    const float* W2  = (const float*)d_in[4];
    const float* b2  = (const float*)d_in[5];
    float* out = (float*)d_out;

    const int N = N_NODES, E = N_EDGES;
    const int* src = ei;
    const int* dst = ei + E;

    char* p = (char*)d_ws;
    auto carve = [&](size_t bytes) -> void* {
        void* r = (void*)p;
        p += (bytes + 511) & ~(size_t)511;
        return r;
    };
    int*      gcnt  = (int*)carve((size_t)NB * 64 * 4);
    int*      gcur  = (int*)carve((size_t)NB * 64 * 4);
    int*      bbase = (int*)carve((size_t)(NB + 1) * 4);
    uint32_t* epk   = (uint32_t*)carve((size_t)E * 4);
    int*      offs  = (int*)carve((size_t)N * 4);
    int*      cnt   = (int*)carve((size_t)N * 4);
    float*    dinv  = (float*)carve((size_t)N * 4);
    int*      ssrc  = (int*)carve((size_t)E * 4);
    ushort*   wbf   = (ushort*)carve((size_t)HID * IN_F * 2);
    uint32_t* hs8   = (uint32_t*)carve((size_t)N * 32 * 4);   // fp8 rows, 128B
    float*    h2s   = (float*)carve((size_t)N * OUT_F * 4);

    hipMemsetAsync(gcnt, 0, (size_t)NB * 64 * 4, stream);

    k_wcast<<<8, 256, 0, stream>>>(W1, wbf);
    k_bhist<<<512, 256, 0, stream>>>(dst, gcnt, E);
    k_bscan<<<1, 512, 0, stream>>>(gcnt, bbase, gcur);
    k_part<<<(E + PASS - 1) / PASS, 512, 0, stream>>>(src, dst, gcur, epk, E);
    k_csr<<<NB, 1024, 0, stream>>>(epk, bbase, offs, cnt, dinv, ssrc, N);

    k_gemm1<<<(N + 63) / 64, 256, 0, stream>>>(x, wbf, dinv, hs8, N);
    k_agg1<<<(N * 64 + 255) / 256, 256, 0, stream>>>(hs8, offs, cnt, dinv, ssrc, b1, W2, h2s, N);
    k_agg2<<<(N * 64 + 255) / 256, 256, 0, stream>>>(h2s, offs, cnt, dinv, ssrc, b2, out, N);
}